// Round 16
// baseline (919.098 us; speedup 1.0000x reference)
//
#include <hip/hip_runtime.h>
#include <hip/hip_bf16.h>

#define DI __device__ __forceinline__

typedef __attribute__((ext_vector_type(8))) short bf16x8;
typedef __attribute__((ext_vector_type(4))) float f32x4;

namespace {
constexpr int B_ = 2048, J_ = 17, C_ = 480, K_ = 3, TOK_ = 64, CH_ = 960, H_ = 6, HD_ = 80;
constexpr int C3_ = 3 * C_;            // 1440
constexpr int NM_ = 2880;              // merged qkv+gcn1 N (= 30*96)
constexpr float EPSF = 1e-5f;
}

// branch-free tanh-form GELU
DI float gelu_f(float x) {
  const float kA2 = 2.f * 0.7978845608028654f;
  const float kB2 = 2.f * 0.7978845608028654f * 0.044715f;
  const float z = fmaf(-kB2 * x, x * x, -kA2 * x);
  return x / (1.f + __expf(z));
}
DI float b2f(__hip_bfloat16 v) { return __bfloat162float(v); }
DI __hip_bfloat16 f2b(float v) { return __float2bfloat16(v); }
DI float s2f(short s) { return __uint_as_float(((unsigned)(unsigned short)s) << 16); }
DI unsigned pk2(float a, float b) {
  union { unsigned u; __hip_bfloat16 h[2]; } p;
  p.h[0] = f2b(a); p.h[1] = f2b(b);
  return p.u;
}

DI void gl16(const void* g, void* l) {
  __builtin_amdgcn_global_load_lds(
      (const __attribute__((address_space(1))) unsigned int*)g,
      (__attribute__((address_space(3))) unsigned int*)l, 16, 0, 0);
}

// ---------------- all weights fp32 -> bf16, one kernel (dst arena contiguous) ----------------
__global__ __launch_bounds__(256) void cvt_all_kernel(
    const float* __restrict__ s0, const float* __restrict__ s1,
    const float* __restrict__ s2, const float* __restrict__ s3,
    const float* __restrict__ s4, const float* __restrict__ s5,
    __hip_bfloat16* __restrict__ d) {
  constexpr int SG = C3_ * C_;                 // 691200
  constexpr int O1 = SG, O2 = 2 * SG, O3 = 3 * SG;
  constexpr int O4 = O3 + C_ * C_;
  constexpr int O5 = O4 + CH_ * C_;
  const int i = (blockIdx.x * 256 + threadIdx.x) * 4;
  const float* s; int off;
  if      (i < O1) { s = s0; off = i; }
  else if (i < O2) { s = s1; off = i - O1; }
  else if (i < O3) { s = s2; off = i - O2; }
  else if (i < O4) { s = s3; off = i - O3; }
  else if (i < O5) { s = s4; off = i - O4; }
  else             { s = s5; off = i - O5; }
  const float4 v = *reinterpret_cast<const float4*>(s + off);
  union { ushort4 u; __hip_bfloat16 h[4]; } o;
  o.h[0] = f2b(v.x); o.h[1] = f2b(v.y); o.h[2] = f2b(v.z); o.h[3] = f2b(v.w);
  *reinterpret_cast<ushort4*>(reinterpret_cast<unsigned short*>(d) + i) = o.u;
}

// ---------------- LayerNorm over J ----------------
__global__ __launch_bounds__(256) void ln1_kernel(const float* __restrict__ x,
                                                  const float* __restrict__ g,
                                                  const float* __restrict__ bt,
                                                  __hip_bfloat16* __restrict__ xnT, int nBC) {
  const int t = blockIdx.x * 256 + threadIdx.x;
  if (t >= nBC) return;
  const int b = t / C_, c = t % C_;
  const float* xp = x + (size_t)b * J_ * C_ + c;
  float v[J_];
  float s = 0.f;
  #pragma unroll
  for (int j = 0; j < J_; ++j) { v[j] = xp[j * C_]; s += v[j]; }
  const float mu = s * (1.f / J_);
  float sq = 0.f;
  #pragma unroll
  for (int j = 0; j < J_; ++j) { const float d = v[j] - mu; sq += d * d; }
  const float rs = rsqrtf(sq * (1.f / J_) + EPSF);
  __hip_bfloat16* op = xnT + (size_t)b * J_ * C_ + c;
  #pragma unroll
  for (int j = 0; j < J_; ++j) op[j * C_] = f2b((v[j] - mu) * rs * g[j] + bt[j]);
}

// ---------------- GEMM: BM=128 x BN=96, 8 waves, BK=64 single-buffer, XCD-swizzled 1D grid ----
// bias = col < bsplit ? bias1[col] : bias2[col-bsplit].
// EPI 0/1: CT-LDS coalesced epilogue. EPI 2: f32 acc+bias+r1+r2.
template<int KD, int EPI>
__global__ __launch_bounds__(512) void gemm_lds(const __hip_bfloat16* __restrict__ A,
                                                const __hip_bfloat16* __restrict__ W,
                                                const float* __restrict__ bias1,
                                                const float* __restrict__ bias2, int bsplit,
                                                __hip_bfloat16* __restrict__ Dst, int Ntot, int nM,
                                                const __hip_bfloat16* __restrict__ r1,
                                                const __hip_bfloat16* __restrict__ r2,
                                                float* __restrict__ outf) {
  constexpr int NST = (KD + 63) / 64;
  constexpr bool TAIL = (KD % 64) != 0;
  constexpr int ROWB = KD * 2;
  __shared__ __align__(16) char smem[28672];   // A[0,16K) B[16K,28K); epi CT 128x208B

  // bijective XCD swizzle (m204): consecutive sid within an XCD chunk share the W panel (m-fastest)
  const int nwg = gridDim.x, id = blockIdx.x;
  const int q = nwg >> 3, r = nwg & 7;
  const int xcd = id & 7, ii = id >> 3;
  const int sid = (xcd < r ? xcd * (q + 1) : r * (q + 1) + (xcd - r) * q) + ii;
  const int m0g = (sid % nM) * 128;
  const int n0g = (sid / nM) * 96;

  const int lane = threadIdx.x & 63;
  const int wid  = threadIdx.x >> 6;
  const int srow = lane >> 3;
  const int scbs = ((lane & 7) * 16) ^ ((srow & 7) << 4);
  auto stage = [&](int t) {
    const int kb = t * 128;
    #pragma unroll
    for (int i = wid; i < 28; i += 8) {
      if (i < 16) {
        const int rr = i * 8 + srow;
        gl16((const char*)A + (size_t)(m0g + rr) * ROWB + kb + scbs, smem + i * 1024);
      } else {
        const int rr = (i - 16) * 8 + srow;
        gl16((const char*)W + (size_t)(n0g + rr) * ROWB + kb + scbs, smem + 16384 + (i - 16) * 1024);
      }
    }
  };

  const f32x4 zf = {0.f, 0.f, 0.f, 0.f};
  f32x4 acc[2][3];
  #pragma unroll
  for (int mi = 0; mi < 2; ++mi)
    #pragma unroll
    for (int ni = 0; ni < 3; ++ni) acc[mi][ni] = zf;

  const int rA0 = (wid >> 1) * 32 + (lane & 15);
  const int rB0 = (wid & 1) * 48 + (lane & 15);
  const int swz = (lane & 7) << 4;
  const int kq  = (lane >> 4) * 16;

  for (int t = 0; t < NST; ++t) {
    stage(t);
    __syncthreads();
    const int nks = (TAIL && t == NST - 1) ? 1 : 2;
    for (int ks = 0; ks < nks; ++ks) {
      const int cb = (ks * 64 + kq) ^ swz;
      bf16x8 av[2], bv[3];
      #pragma unroll
      for (int mi = 0; mi < 2; ++mi)
        av[mi] = *reinterpret_cast<const bf16x8*>(smem + (rA0 + mi * 16) * 128 + cb);
      #pragma unroll
      for (int ni = 0; ni < 3; ++ni)
        bv[ni] = *reinterpret_cast<const bf16x8*>(smem + 16384 + (rB0 + ni * 16) * 128 + cb);
      #pragma unroll
      for (int mi = 0; mi < 2; ++mi)
        #pragma unroll
        for (int ni = 0; ni < 3; ++ni)
          acc[mi][ni] = __builtin_amdgcn_mfma_f32_16x16x32_bf16(av[mi], bv[ni], acc[mi][ni], 0, 0, 0);
    }
    __syncthreads();
  }

  const int lc0 = (wid & 1) * 48 + (lane & 15);
  const int lr0 = (wid >> 1) * 32 + ((lane >> 4) << 2);
  if (EPI == 2) {
    #pragma unroll
    for (int ni = 0; ni < 3; ++ni) {
      const int col = n0g + lc0 + ni * 16;
      const float bvv = (col < bsplit) ? bias1[col] : bias2[col - bsplit];
      #pragma unroll
      for (int mi = 0; mi < 2; ++mi) {
        #pragma unroll
        for (int r4 = 0; r4 < 4; ++r4) {
          const size_t idx = (size_t)(m0g + lr0 + mi * 16 + r4) * Ntot + col;
          outf[idx] = acc[mi][ni][r4] + bvv + b2f(r1[idx]) + b2f(r2[idx]);
        }
      }
    }
  } else {
    __hip_bfloat16* ct = (__hip_bfloat16*)smem;
    #pragma unroll
    for (int ni = 0; ni < 3; ++ni) {
      const int col = n0g + lc0 + ni * 16;
      const float bvv = (col < bsplit) ? bias1[col] : bias2[col - bsplit];
      #pragma unroll
      for (int mi = 0; mi < 2; ++mi) {
        #pragma unroll
        for (int r4 = 0; r4 < 4; ++r4) {
          float v = acc[mi][ni][r4] + bvv;
          if (EPI == 1) v = gelu_f(v);
          ct[(lr0 + mi * 16 + r4) * 104 + lc0 + ni * 16] = f2b(v);
        }
      }
    }
    __syncthreads();
    const int tid = threadIdx.x;
    #pragma unroll
    for (int it = 0; it < 3; ++it) {
      const int idx = it * 512 + tid;              // 1536 = 128 rows x 12 slots
      const int row = idx / 12, s = idx - row * 12;
      const uint4 v = *(const uint4*)(smem + row * 208 + s * 16);
      *(uint4*)((char*)Dst + ((size_t)(m0g + row) * Ntot + n0g) * 2 + s * 16) = v;
    }
  }
}

// ---------------- attention: qkv rows at stride NM (merged buffer, cols 0..1439) ----------------
__global__ __launch_bounds__(512) void attn_kernel(const __hip_bfloat16* __restrict__ qkv,
                                                   __hip_bfloat16* __restrict__ o) {
  constexpr int SROW = 1448;
  const int b = blockIdx.x, tid = threadIdx.x;
  __shared__ __align__(16) __hip_bfloat16 sqkv[J_ * SROW];
  __shared__ float S[H_][J_][J_];
  {
    const uint4* src = (const uint4*)(qkv + (size_t)b * J_ * NM_);
    uint4* dst = (uint4*)&sqkv[0];
    for (int i = tid; i < 3060; i += 512) {
      const int j = i / 180, u = i - j * 180;
      dst[j * 181 + u] = src[j * 360 + u];
    }
  }
  __syncthreads();
  for (int i = tid; i < H_ * J_ * J_; i += 512) {
    const int h = i / (J_ * J_), r = i % (J_ * J_), qj = r / J_, kj = r % J_;
    const bf16x8* qp = (const bf16x8*)&sqkv[qj * SROW + h * HD_];
    const bf16x8* kp = (const bf16x8*)&sqkv[kj * SROW + C_ + h * HD_];
    float acc = 0.f;
    #pragma unroll
    for (int d8 = 0; d8 < HD_ / 8; ++d8) {
      const bf16x8 qv = qp[d8], kv = kp[d8];
      #pragma unroll
      for (int t = 0; t < 8; ++t) acc += s2f(qv[t]) * s2f(kv[t]);
    }
    S[h][qj][kj] = acc * 0.11180339887498949f;
  }
  __syncthreads();
  if (tid < H_ * J_) {
    const int h = tid / J_, qj = tid % J_;
    float* row = S[h][qj];
    float m = row[0];
    #pragma unroll
    for (int kk = 1; kk < J_; ++kk) m = fmaxf(m, row[kk]);
    float s = 0.f;
    #pragma unroll
    for (int kk = 0; kk < J_; ++kk) { const float e = __expf(row[kk] - m); row[kk] = e; s += e; }
    const float inv = 1.f / s;
    #pragma unroll
    for (int kk = 0; kk < J_; ++kk) row[kk] *= inv;
  }
  __syncthreads();
  __hip_bfloat16* ob = o + (size_t)b * J_ * C_;
  for (int i = tid; i < J_ * C_; i += 512) {
    const int qj = i / C_, c = i % C_;
    const int h = c / HD_;
    const float* srow = S[h][qj];
    float acc = 0.f;
    #pragma unroll
    for (int kk = 0; kk < J_; ++kk) acc += srow[kk] * b2f(sqkv[kk * SROW + 2 * C_ + c]);
    ob[i] = f2b(acc);
  }
}

// ---------------- gcn adjacency contraction (row stride ldy, col offset offy) ----------------
__global__ __launch_bounds__(512) void gcn_contract_kernel(const __hip_bfloat16* __restrict__ y,
                                                           const float* __restrict__ adj,
                                                           __hip_bfloat16* __restrict__ g,
                                                           int ldy, int offy) {
  const int b = blockIdx.x, tid = threadIdx.x;
  __shared__ float adjl[K_ * J_ * J_];
  for (int i = tid; i < K_ * J_ * J_; i += 512) adjl[i] = adj[i];
  __syncthreads();
  const int c = tid;
  if (c < C_) {
    float yv[K_][J_];
    const __hip_bfloat16* yb = y + (size_t)b * J_ * ldy + offy + c;
    #pragma unroll
    for (int k = 0; k < K_; ++k)
      #pragma unroll
      for (int v = 0; v < J_; ++v)
        yv[k][v] = b2f(yb[(size_t)v * ldy + k * C_]);
    __hip_bfloat16* gp = g + (size_t)b * J_ * C_ + c;
    #pragma unroll
    for (int w = 0; w < J_; ++w) {
      float acc = 0.f;
      #pragma unroll
      for (int k = 0; k < K_; ++k)
        #pragma unroll
        for (int v = 0; v < J_; ++v)
          acc += yv[k][v] * adjl[(k * J_ + v) * J_ + w];
      gp[w * C_] = f2b(acc);
    }
  }
}

// ---------------- dwconv7 + GroupNorm(16) + GELU -> D'[(b*480+c)][32] ----------------
__global__ __launch_bounds__(512) void dwconv_kernel(const __hip_bfloat16* __restrict__ xnT,
    const float* __restrict__ dww, const float* __restrict__ dwb,
    const float* __restrict__ gg, const float* __restrict__ gb,
    __hip_bfloat16* __restrict__ dpr) {
  __shared__ __align__(16) __hip_bfloat16 xl[J_ * C_];
  __shared__ float gstat[16][2];
  const int b = blockIdx.x, tid = threadIdx.x;
  {
    const uint4* src = (const uint4*)(xnT + (size_t)b * J_ * C_);
    uint4* dst = (uint4*)&xl[0];
    for (int i = tid; i < 1020; i += 512) dst[i] = src[i];
  }
  if (tid < 32) gstat[tid >> 1][tid & 1] = 0.f;
  __syncthreads();
  const int c = tid;
  float dv[J_];
  if (c < C_) {
    float xv[J_];
    #pragma unroll
    for (int j = 0; j < J_; ++j) xv[j] = b2f(xl[j * C_ + c]);
    float wv[7];
    #pragma unroll
    for (int t = 0; t < 7; ++t) wv[t] = dww[c * 7 + t];
    const float bias = dwb[c];
    float s = 0.f, sqs = 0.f;
    #pragma unroll
    for (int j = 0; j < J_; ++j) {
      float acc = bias;
      #pragma unroll
      for (int t = 0; t < 7; ++t) {
        const int jj = j - 3 + t;
        if (jj >= 0 && jj < J_) acc = fmaf(xv[jj], wv[t], acc);
      }
      dv[j] = acc; s += acc; sqs += acc * acc;
    }
    atomicAdd(&gstat[c / 30][0], s);
    atomicAdd(&gstat[c / 30][1], sqs);
  }
  __syncthreads();
  if (c < C_) {
    const float mu = gstat[c / 30][0] * (1.f / 510.f);
    const float var = gstat[c / 30][1] * (1.f / 510.f) - mu * mu;
    const float rs = rsqrtf(var + EPSF);
    const float sc = gg[c], of = gb[c];
    #pragma unroll
    for (int j = 0; j < J_; ++j) dv[j] = gelu_f((dv[j] - mu) * rs * sc + of);
    uint4 q0, q1, q2;
    q0.x = pk2(dv[0], dv[1]);   q0.y = pk2(dv[2], dv[3]);
    q0.z = pk2(dv[4], dv[5]);   q0.w = pk2(dv[6], dv[7]);
    q1.x = pk2(dv[8], dv[9]);   q1.y = pk2(dv[10], dv[11]);
    q1.z = pk2(dv[12], dv[13]); q1.w = pk2(dv[14], dv[15]);
    q2.x = pk2(dv[16], 0.f);    q2.y = 0u; q2.z = 0u; q2.w = 0u;
    const uint4 zq = {0u, 0u, 0u, 0u};
    uint4* rp = (uint4*)(dpr + ((size_t)b * C_ + c) * 32);
    rp[0] = q0; rp[1] = q1; rp[2] = q2; rp[3] = zq;
  }
}

// ---------------- token-MLP on MFMA -> mjem_r[(b*480+c)][20] ----------------
__global__ __launch_bounds__(256) void mlp_kernel(const __hip_bfloat16* __restrict__ dpr,
    const float* __restrict__ w1, const float* __restrict__ b1,
    const float* __restrict__ w2, const float* __restrict__ b2,
    __hip_bfloat16* __restrict__ mjem_r) {
  __shared__ __align__(16) char lds[18944];
  constexpr int W1P = 0, W2P = 5120, HS = 9728;
  const int tid = threadIdx.x, lane = tid & 63, wid = tid >> 6;

  {
    __hip_bfloat16* wp = (__hip_bfloat16*)(lds + W1P);
    const int t = tid >> 2, j0 = (tid & 3) * 10;
    #pragma unroll
    for (int e = 0; e < 10; ++e) {
      const int j = j0 + e;
      wp[t * 40 + j] = (j < J_) ? f2b(w1[t * J_ + j]) : f2b(0.f);
    }
  }
  {
    __hip_bfloat16* wp = (__hip_bfloat16*)(lds + W2P);
    const int j = tid >> 3, t0 = (tid & 7) * 9;
    #pragma unroll
    for (int e = 0; e < 9; ++e) {
      const int t = t0 + e;
      wp[j * 72 + t] = (j < J_ && t < TOK_) ? f2b(w2[j * TOK_ + t]) : f2b(0.f);
    }
  }
  __syncthreads();

  const int lr = lane & 15, kc = lane >> 4;
  bf16x8 a1[4];
  #pragma unroll
  for (int mi = 0; mi < 4; ++mi)
    a1[mi] = *(const bf16x8*)(lds + W1P + (lr + mi * 16) * 80 + kc * 16);
  bf16x8 a2[2][2];
  #pragma unroll
  for (int mi = 0; mi < 2; ++mi)
    #pragma unroll
    for (int kk = 0; kk < 2; ++kk)
      a2[mi][kk] = *(const bf16x8*)(lds + W2P + (lr + mi * 16) * 144 + kk * 64 + kc * 16);
  float b1v[4][4];
  #pragma unroll
  for (int mi = 0; mi < 4; ++mi)
    #pragma unroll
    for (int r = 0; r < 4; ++r) b1v[mi][r] = b1[mi * 16 + kc * 4 + r];
  float b2v[4];
  #pragma unroll
  for (int r = 0; r < 4; ++r) b2v[r] = b2[kc * 4 + r];
  const float b2v16 = b2[16];

  char* hs = lds + HS + wid * 2304;
  const f32x4 zf4 = {0.f, 0.f, 0.f, 0.f};
  #pragma unroll
  for (int it = 0; it < 4; ++it) {
    const int gcb = blockIdx.x * 16 + wid * 4 + it;
    const int b = gcb / 30, cbl = gcb - b * 30;
    const size_t row0 = (size_t)b * C_ + cbl * 16;
    const bf16x8 bf = *(const bf16x8*)(dpr + (row0 + lr) * 32 + kc * 8);
    f32x4 acc1[4];
    #pragma unroll
    for (int mi = 0; mi < 4; ++mi)
      acc1[mi] = __builtin_amdgcn_mfma_f32_16x16x32_bf16(a1[mi], bf, zf4, 0, 0, 0);
    #pragma unroll
    for (int mi = 0; mi < 4; ++mi) {
      const float g0 = gelu_f(acc1[mi][0] + b1v[mi][0]);
      const float g1 = gelu_f(acc1[mi][1] + b1v[mi][1]);
      const float g2 = gelu_f(acc1[mi][2] + b1v[mi][2]);
      const float g3 = gelu_f(acc1[mi][3] + b1v[mi][3]);
      unsigned* hp = (unsigned*)(hs + lr * 144 + (mi * 16 + kc * 4) * 2);
      hp[0] = pk2(g0, g1);
      hp[1] = pk2(g2, g3);
    }
    f32x4 acc2[2] = {zf4, zf4};
    #pragma unroll
    for (int kk = 0; kk < 2; ++kk) {
      const bf16x8 hb = *(const bf16x8*)(hs + lr * 144 + kk * 64 + kc * 16);
      #pragma unroll
      for (int mi = 0; mi < 2; ++mi)
        acc2[mi] = __builtin_amdgcn_mfma_f32_16x16x32_bf16(a2[mi][kk], hb, acc2[mi], 0, 0, 0);
    }
    __hip_bfloat16* mp = mjem_r + (row0 + lr) * 20;
    #pragma unroll
    for (int r = 0; r < 4; ++r)
      mp[kc * 4 + r] = f2b(acc2[0][r] + b2v[r]);
    if (kc == 0) mp[16] = f2b(acc2[1][0] + b2v16);
  }
}

// ---------------- fuse: inline g1-contraction + pos-conv + sum + GN + GELU + residual + LN2 ----
__global__ __launch_bounds__(512) void fuse_kernel(
    const float* __restrict__ x, const __hip_bfloat16* __restrict__ xnT,
    const __hip_bfloat16* __restrict__ y1, const float* __restrict__ adj,
    const __hip_bfloat16* __restrict__ projo, const __hip_bfloat16* __restrict__ mjem_r,
    const float* __restrict__ posw, const float* __restrict__ posb,
    const float* __restrict__ gnfg, const float* __restrict__ gnfb,
    const float* __restrict__ n2g, const float* __restrict__ n2b,
    __hip_bfloat16* __restrict__ resch, __hip_bfloat16* __restrict__ xn2) {
  const int b = blockIdx.x, tid = threadIdx.x;
  __shared__ float xcl[J_][C_];
  __shared__ float adjl[K_ * J_ * J_];
  __shared__ float gstat[16][2];
  __shared__ float lnst[J_][2];
  for (int i = tid; i < K_ * J_ * J_; i += 512) adjl[i] = adj[i];
  if (tid < 32) gstat[tid >> 1][tid & 1] = 0.f;
  __syncthreads();
  const int c = tid;
  float fz[J_];
  if (c < C_) {
    float xnv[J_];
    const __hip_bfloat16* xp = xnT + (size_t)b * J_ * C_ + c;
    #pragma unroll
    for (int j = 0; j < J_; ++j) xnv[j] = b2f(xp[j * C_]);
    float pw[9];
    #pragma unroll
    for (int t = 0; t < 9; ++t) pw[t] = posw[c * 9 + t];
    const float pb = posb[c];
    const __hip_bfloat16* pj = projo + (size_t)b * J_ * C_ + c;
    const __hip_bfloat16* mp = mjem_r + ((size_t)b * C_ + c) * 20;
    // base terms
    #pragma unroll
    for (int j = 0; j < J_; ++j) {
      float pos = pb;
      #pragma unroll
      for (int t = 0; t < 9; ++t) {
        const int jj = j - 4 + t;
        if (jj >= 0 && jj < J_) pos += xnv[jj] * pw[t];
      }
      fz[j] = b2f(pj[j * C_]) + pos + b2f(mp[j]);
    }
    // inline g1 contraction: k-outer keeps only 17 y regs live
    const __hip_bfloat16* yb = y1 + (size_t)b * J_ * NM_ + C3_ + c;   // cols 1440.. of merged
    #pragma unroll
    for (int k = 0; k < K_; ++k) {
      float yv[J_];
      #pragma unroll
      for (int v = 0; v < J_; ++v) yv[v] = b2f(yb[(size_t)v * NM_ + k * C_]);
      #pragma unroll
      for (int j = 0; j < J_; ++j) {
        float acc = 0.f;
        #pragma unroll
        for (int v = 0; v < J_; ++v) acc = fmaf(yv[v], adjl[(k * J_ + v) * J_ + j], acc);
        fz[j] += acc;
      }
    }
    float s = 0.f, sqs = 0.f;
    #pragma unroll
    for (int j = 0; j < J_; ++j) { s += fz[j]; sqs += fz[j] * fz[j]; }
    atomicAdd(&gstat[c / 30][0], s);
    atomicAdd(&gstat[c / 30][1], sqs);
  }
  __syncthreads();
  if (c < C_) {
    const float mu = gstat[c / 30][0] * (1.f / 510.f);
    const float var = gstat[c / 30][1] * (1.f / 510.f) - mu * mu;
    const float rs = rsqrtf(var + EPSF);
    const float sc = gnfg[c], of = gnfb[c];
    const float* xr = x + (size_t)b * J_ * C_ + c;
    __hip_bfloat16* rp = resch + (size_t)b * J_ * C_ + c;
    #pragma unroll
    for (int j = 0; j < J_; ++j) {
      const float xcv = xr[j * C_] + gelu_f((fz[j] - mu) * rs * sc + of);
      xcl[j][c] = xcv;
      rp[j * C_] = f2b(xcv);
    }
  }
  __syncthreads();
  const int wid = tid >> 6, lane = tid & 63;
  for (int j = wid; j < J_; j += 8) {
    float ls = 0.f, lq = 0.f;
    for (int cc = lane; cc < C_; cc += 64) { const float v = xcl[j][cc]; ls += v; lq += v * v; }
    #pragma unroll
    for (int off = 32; off > 0; off >>= 1) { ls += __shfl_xor(ls, off); lq += __shfl_xor(lq, off); }
    if (lane == 0) {
      const float mu = ls * (1.f / C_);
      const float var = lq * (1.f / C_) - mu * mu;
      lnst[j][0] = mu; lnst[j][1] = rsqrtf(var + EPSF);
    }
  }
  __syncthreads();
  if (c < C_) {
    const float sc = n2g[c], of = n2b[c];
    __hip_bfloat16* xp2 = xn2 + (size_t)b * J_ * C_ + c;
    #pragma unroll
    for (int j = 0; j < J_; ++j)
      xp2[j * C_] = f2b((xcl[j][c] - lnst[j][0]) * lnst[j][1] * sc + of);
  }
}

extern "C" void kernel_launch(void* const* d_in, const int* in_sizes, int n_in,
                              void* d_out, int out_size, void* d_ws, size_t ws_size,
                              hipStream_t stream) {
  const float* x      = (const float*)d_in[0];
  const float* adj    = (const float*)d_in[1];
  const float* n1g    = (const float*)d_in[2];
  const float* n1b    = (const float*)d_in[3];
  const float* gcn1_w = (const float*)d_in[4];
  const float* gcn1_b = (const float*)d_in[5];
  const float* dw_w   = (const float*)d_in[6];
  const float* dw_b   = (const float*)d_in[7];
  const float* dwgn_g = (const float*)d_in[8];
  const float* dwgn_b = (const float*)d_in[9];
  const float* m1w1   = (const float*)d_in[10];
  const float* m1b1   = (const float*)d_in[11];
  const float* m1w2   = (const float*)d_in[12];
  const float* m1b2   = (const float*)d_in[13];
  const float* qkv_w  = (const float*)d_in[14];
  const float* qkv_b  = (const float*)d_in[15];
  const float* proj_w = (const float*)d_in[16];
  const float* proj_b = (const float*)d_in[17];
  const float* pos_w  = (const float*)d_in[18];
  const float* pos_b  = (const float*)d_in[19];
  const float* gnf_g  = (const float*)d_in[20];
  const float* gnf_b  = (const float*)d_in[21];
  const float* n2g    = (const float*)d_in[22];
  const float* n2b    = (const float*)d_in[23];
  const float* gcn2_w = (const float*)d_in[24];
  const float* gcn2_b = (const float*)d_in[25];
  const float* m2w1   = (const float*)d_in[26];
  const float* m2b1   = (const float*)d_in[27];
  const float* m2w2   = (const float*)d_in[28];
  const float* m2b2   = (const float*)d_in[29];
  float* out = (float*)d_out;
  char* ws = (char*)d_ws;
  (void)in_sizes; (void)n_in; (void)out_size;

  auto a256 = [](size_t b) { return (b + 255) & ~(size_t)255; };
  const size_t wbytes = 3 * a256((size_t)C3_ * C_ * 2) + a256((size_t)C_ * C_ * 2) +
                        a256((size_t)CH_ * C_ * 2) + a256((size_t)C_ * CH_ * 2);
  int nch = 16;
  for (int cand : {1, 2, 4, 8, 16}) {
    const size_t Bcb = (size_t)(B_ / cand);
    const size_t Mcb = Bcb * J_;
    const size_t fp = wbytes + a256(Mcb * NM_ * 2) + 5 * a256(Mcb * C_ * 2) +
                      a256(Bcb * C_ * 20 * 2) + a256(Bcb * C_ * 32 * 2);
    if (fp <= ws_size) { nch = cand; break; }
  }
  const int Bc = B_ / nch;
  const int Mc = Bc * J_;
  const int nMB = Mc / 128;

  size_t off = 0;
  auto alloc = [&](size_t bytes) { char* p = ws + off; off += a256(bytes); return p; };
  // weight arena: qkv & g1 contiguous (merged GEMM reads 2880 rows starting at w_qkv)
  __hip_bfloat16* w_qkv = (__hip_bfloat16*)alloc((size_t)C3_ * C_ * 2);
  __hip_bfloat16* w_g1  = (__hip_bfloat16*)alloc((size_t)C3_ * C_ * 2);
  __hip_bfloat16* w_g2  = (__hip_bfloat16*)alloc((size_t)C3_ * C_ * 2);
  __hip_bfloat16* w_pr  = (__hip_bfloat16*)alloc((size_t)C_ * C_ * 2);
  __hip_bfloat16* w_21  = (__hip_bfloat16*)alloc((size_t)CH_ * C_ * 2);
  __hip_bfloat16* w_22  = (__hip_bfloat16*)alloc((size_t)C_ * CH_ * 2);
  __hip_bfloat16* BIG   = (__hip_bfloat16*)alloc((size_t)Mc * NM_ * 2);  // merged qkv+y1 -> y2 -> hbuf
  __hip_bfloat16* xnT   = (__hip_bfloat16*)alloc((size_t)Mc * C_ * 2);
  __hip_bfloat16* attno = (__hip_bfloat16*)alloc((size_t)Mc * C_ * 2);   // -> xn2
  __hip_bfloat16* projo = (__hip_bfloat16*)alloc((size_t)Mc * C_ * 2);
  __hip_bfloat16* g2o   = (__hip_bfloat16*)alloc((size_t)Mc * C_ * 2);
  __hip_bfloat16* resch = (__hip_bfloat16*)alloc((size_t)Mc * C_ * 2);
  __hip_bfloat16* mjemr = (__hip_bfloat16*)alloc((size_t)Bc * C_ * 20 * 2);
  __hip_bfloat16* dpr   = (__hip_bfloat16*)alloc((size_t)Bc * C_ * 32 * 2);
  __hip_bfloat16* xn2   = attno;
  __hip_bfloat16* hbuf  = BIG;
  (void)w_g1;

  cvt_all_kernel<<<3150, 256, 0, stream>>>(qkv_w, gcn1_w, gcn2_w, proj_w, m2w1, m2w2, w_qkv);

  for (int ci = 0; ci < nch; ++ci) {
    const float* xc = x + (size_t)ci * Bc * J_ * C_;
    float* outc = out + (size_t)ci * Bc * J_ * C_;
    ln1_kernel<<<(Bc * C_ + 255) / 256, 256, 0, stream>>>(xc, n1g, n1b, xnT, Bc * C_);
    // merged qkv + gcn1 GEMM: N = 2880, bias split at 1440
    gemm_lds<C_, 0><<<nMB * (NM_ / 96), 512, 0, stream>>>(xnT, w_qkv, qkv_b, gcn1_b, C3_,
                                                          BIG, NM_, nMB, nullptr, nullptr, nullptr);
    attn_kernel<<<Bc, 512, 0, stream>>>(BIG, attno);
    gemm_lds<C_, 0><<<nMB * (C_ / 96), 512, 0, stream>>>(attno, w_pr, proj_b, proj_b, C_,
                                                         projo, C_, nMB, nullptr, nullptr, nullptr);
    dwconv_kernel<<<Bc, 512, 0, stream>>>(xnT, dw_w, dw_b, dwgn_g, dwgn_b, dpr);
    mlp_kernel<<<Bc * 30 / 16, 256, 0, stream>>>(dpr, m1w1, m1b1, m1w2, m1b2, mjemr);
    fuse_kernel<<<Bc, 512, 0, stream>>>(xc, xnT, BIG, adj, projo, mjemr, pos_w, pos_b,
                                        gnf_g, gnf_b, n2g, n2b, resch, xn2);
    // channel stage
    gemm_lds<C_, 0><<<nMB * (C3_ / 96), 512, 0, stream>>>(xn2, w_g2, gcn2_b, gcn2_b, C3_,
                                                          BIG, C3_, nMB, nullptr, nullptr, nullptr);
    gcn_contract_kernel<<<Bc, 512, 0, stream>>>(BIG, adj, g2o, C3_, 0);
    gemm_lds<C_, 1><<<nMB * (CH_ / 96), 512, 0, stream>>>(xn2, w_21, m2b1, m2b1, CH_,
                                                          hbuf, CH_, nMB, nullptr, nullptr, nullptr);
    gemm_lds<CH_, 2><<<nMB * (C_ / 96), 512, 0, stream>>>(hbuf, w_22, m2b2, m2b2, C_,
                                                          nullptr, C_, nMB, resch, g2o, outc);
  }
}

// Round 17
// 853.749 us; speedup vs baseline: 1.0765x; 1.0765x over previous
//
#include <hip/hip_runtime.h>
#include <hip/hip_bf16.h>

#define DI __device__ __forceinline__

typedef __attribute__((ext_vector_type(8))) short bf16x8;
typedef __attribute__((ext_vector_type(4))) float f32x4;

namespace {
constexpr int B_ = 2048, J_ = 17, C_ = 480, K_ = 3, TOK_ = 64, CH_ = 960, H_ = 6, HD_ = 80;
constexpr int C3_ = 3 * C_;            // 1440
constexpr int NM_ = 2880;              // merged qkv+gcn1 N (= 30*96)
constexpr float EPSF = 1e-5f;
}

// branch-free tanh-form GELU
DI float gelu_f(float x) {
  const float kA2 = 2.f * 0.7978845608028654f;
  const float kB2 = 2.f * 0.7978845608028654f * 0.044715f;
  const float z = fmaf(-kB2 * x, x * x, -kA2 * x);
  return x / (1.f + __expf(z));
}
DI float b2f(__hip_bfloat16 v) { return __bfloat162float(v); }
DI __hip_bfloat16 f2b(float v) { return __float2bfloat16(v); }
DI float s2f(short s) { return __uint_as_float(((unsigned)(unsigned short)s) << 16); }
DI unsigned pk2(float a, float b) {
  union { unsigned u; __hip_bfloat16 h[2]; } p;
  p.h[0] = f2b(a); p.h[1] = f2b(b);
  return p.u;
}

DI void gl16(const void* g, void* l) {
  __builtin_amdgcn_global_load_lds(
      (const __attribute__((address_space(1))) unsigned int*)g,
      (__attribute__((address_space(3))) unsigned int*)l, 16, 0, 0);
}

// ---------------- all weights fp32 -> bf16, one kernel (dst arena contiguous) ----------------
__global__ __launch_bounds__(256) void cvt_all_kernel(
    const float* __restrict__ s0, const float* __restrict__ s1,
    const float* __restrict__ s2, const float* __restrict__ s3,
    const float* __restrict__ s4, const float* __restrict__ s5,
    __hip_bfloat16* __restrict__ d) {
  constexpr int SG = C3_ * C_;                 // 691200
  constexpr int O1 = SG, O2 = 2 * SG, O3 = 3 * SG;
  constexpr int O4 = O3 + C_ * C_;
  constexpr int O5 = O4 + CH_ * C_;
  const int i = (blockIdx.x * 256 + threadIdx.x) * 4;
  const float* s; int off;
  if      (i < O1) { s = s0; off = i; }
  else if (i < O2) { s = s1; off = i - O1; }
  else if (i < O3) { s = s2; off = i - O2; }
  else if (i < O4) { s = s3; off = i - O3; }
  else if (i < O5) { s = s4; off = i - O4; }
  else             { s = s5; off = i - O5; }
  const float4 v = *reinterpret_cast<const float4*>(s + off);
  union { ushort4 u; __hip_bfloat16 h[4]; } o;
  o.h[0] = f2b(v.x); o.h[1] = f2b(v.y); o.h[2] = f2b(v.z); o.h[3] = f2b(v.w);
  *reinterpret_cast<ushort4*>(reinterpret_cast<unsigned short*>(d) + i) = o.u;
}

// ---------------- LayerNorm over J ----------------
__global__ __launch_bounds__(256) void ln1_kernel(const float* __restrict__ x,
                                                  const float* __restrict__ g,
                                                  const float* __restrict__ bt,
                                                  __hip_bfloat16* __restrict__ xnT, int nBC) {
  const int t = blockIdx.x * 256 + threadIdx.x;
  if (t >= nBC) return;
  const int b = t / C_, c = t % C_;
  const float* xp = x + (size_t)b * J_ * C_ + c;
  float v[J_];
  float s = 0.f;
  #pragma unroll
  for (int j = 0; j < J_; ++j) { v[j] = xp[j * C_]; s += v[j]; }
  const float mu = s * (1.f / J_);
  float sq = 0.f;
  #pragma unroll
  for (int j = 0; j < J_; ++j) { const float d = v[j] - mu; sq += d * d; }
  const float rs = rsqrtf(sq * (1.f / J_) + EPSF);
  __hip_bfloat16* op = xnT + (size_t)b * J_ * C_ + c;
  #pragma unroll
  for (int j = 0; j < J_; ++j) op[j * C_] = f2b((v[j] - mu) * rs * g[j] + bt[j]);
}

// ---------------- GEMM: BM=128 x BN=96, 8 waves, BK=64 single-buffer, plain 2D grid ----------
// bias = col < bsplit ? bias1[col] : bias2[col-bsplit].
// EPI 0/1: CT-LDS coalesced epilogue. EPI 2: f32 acc+bias+r1+r2.
template<int KD, int EPI>
__global__ __launch_bounds__(512) void gemm_lds(const __hip_bfloat16* __restrict__ A,
                                                const __hip_bfloat16* __restrict__ W,
                                                const float* __restrict__ bias1,
                                                const float* __restrict__ bias2, int bsplit,
                                                __hip_bfloat16* __restrict__ Dst, int Ntot,
                                                const __hip_bfloat16* __restrict__ r1,
                                                const __hip_bfloat16* __restrict__ r2,
                                                float* __restrict__ outf) {
  constexpr int NST = (KD + 63) / 64;
  constexpr bool TAIL = (KD % 64) != 0;
  constexpr int ROWB = KD * 2;
  __shared__ __align__(16) char smem[28672];   // A[0,16K) B[16K,28K); epi CT 128x208B

  const int m0g = blockIdx.x * 128;
  const int n0g = blockIdx.y * 96;

  const int lane = threadIdx.x & 63;
  const int wid  = threadIdx.x >> 6;
  const int srow = lane >> 3;
  const int scbs = ((lane & 7) * 16) ^ ((srow & 7) << 4);
  auto stage = [&](int t) {
    const int kb = t * 128;
    #pragma unroll
    for (int i = wid; i < 28; i += 8) {
      if (i < 16) {
        const int rr = i * 8 + srow;
        gl16((const char*)A + (size_t)(m0g + rr) * ROWB + kb + scbs, smem + i * 1024);
      } else {
        const int rr = (i - 16) * 8 + srow;
        gl16((const char*)W + (size_t)(n0g + rr) * ROWB + kb + scbs, smem + 16384 + (i - 16) * 1024);
      }
    }
  };

  const f32x4 zf = {0.f, 0.f, 0.f, 0.f};
  f32x4 acc[2][3];
  #pragma unroll
  for (int mi = 0; mi < 2; ++mi)
    #pragma unroll
    for (int ni = 0; ni < 3; ++ni) acc[mi][ni] = zf;

  const int rA0 = (wid >> 1) * 32 + (lane & 15);
  const int rB0 = (wid & 1) * 48 + (lane & 15);
  const int swz = (lane & 7) << 4;
  const int kq  = (lane >> 4) * 16;

  for (int t = 0; t < NST; ++t) {
    stage(t);
    __syncthreads();
    const int nks = (TAIL && t == NST - 1) ? 1 : 2;
    for (int ks = 0; ks < nks; ++ks) {
      const int cb = (ks * 64 + kq) ^ swz;
      bf16x8 av[2], bv[3];
      #pragma unroll
      for (int mi = 0; mi < 2; ++mi)
        av[mi] = *reinterpret_cast<const bf16x8*>(smem + (rA0 + mi * 16) * 128 + cb);
      #pragma unroll
      for (int ni = 0; ni < 3; ++ni)
        bv[ni] = *reinterpret_cast<const bf16x8*>(smem + 16384 + (rB0 + ni * 16) * 128 + cb);
      #pragma unroll
      for (int mi = 0; mi < 2; ++mi)
        #pragma unroll
        for (int ni = 0; ni < 3; ++ni)
          acc[mi][ni] = __builtin_amdgcn_mfma_f32_16x16x32_bf16(av[mi], bv[ni], acc[mi][ni], 0, 0, 0);
    }
    __syncthreads();
  }

  const int lc0 = (wid & 1) * 48 + (lane & 15);
  const int lr0 = (wid >> 1) * 32 + ((lane >> 4) << 2);
  if (EPI == 2) {
    #pragma unroll
    for (int ni = 0; ni < 3; ++ni) {
      const int col = n0g + lc0 + ni * 16;
      const float bvv = (col < bsplit) ? bias1[col] : bias2[col - bsplit];
      #pragma unroll
      for (int mi = 0; mi < 2; ++mi) {
        #pragma unroll
        for (int r4 = 0; r4 < 4; ++r4) {
          const size_t idx = (size_t)(m0g + lr0 + mi * 16 + r4) * Ntot + col;
          outf[idx] = acc[mi][ni][r4] + bvv + b2f(r1[idx]) + b2f(r2[idx]);
        }
      }
    }
  } else {
    __hip_bfloat16* ct = (__hip_bfloat16*)smem;
    #pragma unroll
    for (int ni = 0; ni < 3; ++ni) {
      const int col = n0g + lc0 + ni * 16;
      const float bvv = (col < bsplit) ? bias1[col] : bias2[col - bsplit];
      #pragma unroll
      for (int mi = 0; mi < 2; ++mi) {
        #pragma unroll
        for (int r4 = 0; r4 < 4; ++r4) {
          float v = acc[mi][ni][r4] + bvv;
          if (EPI == 1) v = gelu_f(v);
          ct[(lr0 + mi * 16 + r4) * 104 + lc0 + ni * 16] = f2b(v);
        }
      }
    }
    __syncthreads();
    const int tid = threadIdx.x;
    #pragma unroll
    for (int it = 0; it < 3; ++it) {
      const int idx = it * 512 + tid;              // 1536 = 128 rows x 12 slots
      const int row = idx / 12, s = idx - row * 12;
      const uint4 v = *(const uint4*)(smem + row * 208 + s * 16);
      *(uint4*)((char*)Dst + ((size_t)(m0g + row) * Ntot + n0g) * 2 + s * 16) = v;
    }
  }
}

// ---------------- attention: qkv rows at stride NM (merged buffer, cols 0..1439) ----------------
__global__ __launch_bounds__(512) void attn_kernel(const __hip_bfloat16* __restrict__ qkv,
                                                   __hip_bfloat16* __restrict__ o) {
  constexpr int SROW = 1448;
  const int b = blockIdx.x, tid = threadIdx.x;
  __shared__ __align__(16) __hip_bfloat16 sqkv[J_ * SROW];
  __shared__ float S[H_][J_][J_];
  {
    const uint4* src = (const uint4*)(qkv + (size_t)b * J_ * NM_);
    uint4* dst = (uint4*)&sqkv[0];
    for (int i = tid; i < 3060; i += 512) {
      const int j = i / 180, u = i - j * 180;
      dst[j * 181 + u] = src[j * 360 + u];
    }
  }
  __syncthreads();
  for (int i = tid; i < H_ * J_ * J_; i += 512) {
    const int h = i / (J_ * J_), r = i % (J_ * J_), qj = r / J_, kj = r % J_;
    const bf16x8* qp = (const bf16x8*)&sqkv[qj * SROW + h * HD_];
    const bf16x8* kp = (const bf16x8*)&sqkv[kj * SROW + C_ + h * HD_];
    float acc = 0.f;
    #pragma unroll
    for (int d8 = 0; d8 < HD_ / 8; ++d8) {
      const bf16x8 qv = qp[d8], kv = kp[d8];
      #pragma unroll
      for (int t = 0; t < 8; ++t) acc += s2f(qv[t]) * s2f(kv[t]);
    }
    S[h][qj][kj] = acc * 0.11180339887498949f;
  }
  __syncthreads();
  if (tid < H_ * J_) {
    const int h = tid / J_, qj = tid % J_;
    float* row = S[h][qj];
    float m = row[0];
    #pragma unroll
    for (int kk = 1; kk < J_; ++kk) m = fmaxf(m, row[kk]);
    float s = 0.f;
    #pragma unroll
    for (int kk = 0; kk < J_; ++kk) { const float e = __expf(row[kk] - m); row[kk] = e; s += e; }
    const float inv = 1.f / s;
    #pragma unroll
    for (int kk = 0; kk < J_; ++kk) row[kk] *= inv;
  }
  __syncthreads();
  __hip_bfloat16* ob = o + (size_t)b * J_ * C_;
  for (int i = tid; i < J_ * C_; i += 512) {
    const int qj = i / C_, c = i % C_;
    const int h = c / HD_;
    const float* srow = S[h][qj];
    float acc = 0.f;
    #pragma unroll
    for (int kk = 0; kk < J_; ++kk) acc += srow[kk] * b2f(sqkv[kk * SROW + 2 * C_ + c]);
    ob[i] = f2b(acc);
  }
}

// ---------------- gcn adjacency contraction (row stride ldy, col offset offy) ----------------
__global__ __launch_bounds__(512) void gcn_contract_kernel(const __hip_bfloat16* __restrict__ y,
                                                           const float* __restrict__ adj,
                                                           __hip_bfloat16* __restrict__ g,
                                                           int ldy, int offy) {
  const int b = blockIdx.x, tid = threadIdx.x;
  __shared__ float adjl[K_ * J_ * J_];
  for (int i = tid; i < K_ * J_ * J_; i += 512) adjl[i] = adj[i];
  __syncthreads();
  const int c = tid;
  if (c < C_) {
    float yv[K_][J_];
    const __hip_bfloat16* yb = y + (size_t)b * J_ * ldy + offy + c;
    #pragma unroll
    for (int k = 0; k < K_; ++k)
      #pragma unroll
      for (int v = 0; v < J_; ++v)
        yv[k][v] = b2f(yb[(size_t)v * ldy + k * C_]);
    __hip_bfloat16* gp = g + (size_t)b * J_ * C_ + c;
    #pragma unroll
    for (int w = 0; w < J_; ++w) {
      float acc = 0.f;
      #pragma unroll
      for (int k = 0; k < K_; ++k)
        #pragma unroll
        for (int v = 0; v < J_; ++v)
          acc += yv[k][v] * adjl[(k * J_ + v) * J_ + w];
      gp[w * C_] = f2b(acc);
    }
  }
}

// ---------------- dwconv7 + GroupNorm(16) + GELU -> D'[(b*480+c)][32] ----------------
__global__ __launch_bounds__(512) void dwconv_kernel(const __hip_bfloat16* __restrict__ xnT,
    const float* __restrict__ dww, const float* __restrict__ dwb,
    const float* __restrict__ gg, const float* __restrict__ gb,
    __hip_bfloat16* __restrict__ dpr) {
  __shared__ __align__(16) __hip_bfloat16 xl[J_ * C_];
  __shared__ float gstat[16][2];
  const int b = blockIdx.x, tid = threadIdx.x;
  {
    const uint4* src = (const uint4*)(xnT + (size_t)b * J_ * C_);
    uint4* dst = (uint4*)&xl[0];
    for (int i = tid; i < 1020; i += 512) dst[i] = src[i];
  }
  if (tid < 32) gstat[tid >> 1][tid & 1] = 0.f;
  __syncthreads();
  const int c = tid;
  float dv[J_];
  if (c < C_) {
    float xv[J_];
    #pragma unroll
    for (int j = 0; j < J_; ++j) xv[j] = b2f(xl[j * C_ + c]);
    float wv[7];
    #pragma unroll
    for (int t = 0; t < 7; ++t) wv[t] = dww[c * 7 + t];
    const float bias = dwb[c];
    float s = 0.f, sqs = 0.f;
    #pragma unroll
    for (int j = 0; j < J_; ++j) {
      float acc = bias;
      #pragma unroll
      for (int t = 0; t < 7; ++t) {
        const int jj = j - 3 + t;
        if (jj >= 0 && jj < J_) acc = fmaf(xv[jj], wv[t], acc);
      }
      dv[j] = acc; s += acc; sqs += acc * acc;
    }
    atomicAdd(&gstat[c / 30][0], s);
    atomicAdd(&gstat[c / 30][1], sqs);
  }
  __syncthreads();
  if (c < C_) {
    const float mu = gstat[c / 30][0] * (1.f / 510.f);
    const float var = gstat[c / 30][1] * (1.f / 510.f) - mu * mu;
    const float rs = rsqrtf(var + EPSF);
    const float sc = gg[c], of = gb[c];
    #pragma unroll
    for (int j = 0; j < J_; ++j) dv[j] = gelu_f((dv[j] - mu) * rs * sc + of);
    uint4 q0, q1, q2;
    q0.x = pk2(dv[0], dv[1]);   q0.y = pk2(dv[2], dv[3]);
    q0.z = pk2(dv[4], dv[5]);   q0.w = pk2(dv[6], dv[7]);
    q1.x = pk2(dv[8], dv[9]);   q1.y = pk2(dv[10], dv[11]);
    q1.z = pk2(dv[12], dv[13]); q1.w = pk2(dv[14], dv[15]);
    q2.x = pk2(dv[16], 0.f);    q2.y = 0u; q2.z = 0u; q2.w = 0u;
    const uint4 zq = {0u, 0u, 0u, 0u};
    uint4* rp = (uint4*)(dpr + ((size_t)b * C_ + c) * 32);
    rp[0] = q0; rp[1] = q1; rp[2] = q2; rp[3] = zq;
  }
}

// ---------------- token-MLP on MFMA -> mjem_r[(b*480+c)][20] ----------------
__global__ __launch_bounds__(256) void mlp_kernel(const __hip_bfloat16* __restrict__ dpr,
    const float* __restrict__ w1, const float* __restrict__ b1,
    const float* __restrict__ w2, const float* __restrict__ b2,
    __hip_bfloat16* __restrict__ mjem_r) {
  __shared__ __align__(16) char lds[18944];
  constexpr int W1P = 0, W2P = 5120, HS = 9728;
  const int tid = threadIdx.x, lane = tid & 63, wid = tid >> 6;

  {
    __hip_bfloat16* wp = (__hip_bfloat16*)(lds + W1P);
    const int t = tid >> 2, j0 = (tid & 3) * 10;
    #pragma unroll
    for (int e = 0; e < 10; ++e) {
      const int j = j0 + e;
      wp[t * 40 + j] = (j < J_) ? f2b(w1[t * J_ + j]) : f2b(0.f);
    }
  }
  {
    __hip_bfloat16* wp = (__hip_bfloat16*)(lds + W2P);
    const int j = tid >> 3, t0 = (tid & 7) * 9;
    #pragma unroll
    for (int e = 0; e < 9; ++e) {
      const int t = t0 + e;
      wp[j * 72 + t] = (j < J_ && t < TOK_) ? f2b(w2[j * TOK_ + t]) : f2b(0.f);
    }
  }
  __syncthreads();

  const int lr = lane & 15, kc = lane >> 4;
  bf16x8 a1[4];
  #pragma unroll
  for (int mi = 0; mi < 4; ++mi)
    a1[mi] = *(const bf16x8*)(lds + W1P + (lr + mi * 16) * 80 + kc * 16);
  bf16x8 a2[2][2];
  #pragma unroll
  for (int mi = 0; mi < 2; ++mi)
    #pragma unroll
    for (int kk = 0; kk < 2; ++kk)
      a2[mi][kk] = *(const bf16x8*)(lds + W2P + (lr + mi * 16) * 144 + kk * 64 + kc * 16);
  float b1v[4][4];
  #pragma unroll
  for (int mi = 0; mi < 4; ++mi)
    #pragma unroll
    for (int r = 0; r < 4; ++r) b1v[mi][r] = b1[mi * 16 + kc * 4 + r];
  float b2v[4];
  #pragma unroll
  for (int r = 0; r < 4; ++r) b2v[r] = b2[kc * 4 + r];
  const float b2v16 = b2[16];

  char* hs = lds + HS + wid * 2304;
  const f32x4 zf4 = {0.f, 0.f, 0.f, 0.f};
  #pragma unroll
  for (int it = 0; it < 4; ++it) {
    const int gcb = blockIdx.x * 16 + wid * 4 + it;
    const int b = gcb / 30, cbl = gcb - b * 30;
    const size_t row0 = (size_t)b * C_ + cbl * 16;
    const bf16x8 bf = *(const bf16x8*)(dpr + (row0 + lr) * 32 + kc * 8);
    f32x4 acc1[4];
    #pragma unroll
    for (int mi = 0; mi < 4; ++mi)
      acc1[mi] = __builtin_amdgcn_mfma_f32_16x16x32_bf16(a1[mi], bf, zf4, 0, 0, 0);
    #pragma unroll
    for (int mi = 0; mi < 4; ++mi) {
      const float g0 = gelu_f(acc1[mi][0] + b1v[mi][0]);
      const float g1 = gelu_f(acc1[mi][1] + b1v[mi][1]);
      const float g2 = gelu_f(acc1[mi][2] + b1v[mi][2]);
      const float g3 = gelu_f(acc1[mi][3] + b1v[mi][3]);
      unsigned* hp = (unsigned*)(hs + lr * 144 + (mi * 16 + kc * 4) * 2);
      hp[0] = pk2(g0, g1);
      hp[1] = pk2(g2, g3);
    }
    f32x4 acc2[2] = {zf4, zf4};
    #pragma unroll
    for (int kk = 0; kk < 2; ++kk) {
      const bf16x8 hb = *(const bf16x8*)(hs + lr * 144 + kk * 64 + kc * 16);
      #pragma unroll
      for (int mi = 0; mi < 2; ++mi)
        acc2[mi] = __builtin_amdgcn_mfma_f32_16x16x32_bf16(a2[mi][kk], hb, acc2[mi], 0, 0, 0);
    }
    __hip_bfloat16* mp = mjem_r + (row0 + lr) * 20;
    #pragma unroll
    for (int r = 0; r < 4; ++r)
      mp[kc * 4 + r] = f2b(acc2[0][r] + b2v[r]);
    if (kc == 0) mp[16] = f2b(acc2[1][0] + b2v16);
  }
}

// ---------------- fuse: inline g1-contraction + pos-conv + sum + GN + GELU + residual + LN2 ----
__global__ __launch_bounds__(512) void fuse_kernel(
    const float* __restrict__ x, const __hip_bfloat16* __restrict__ xnT,
    const __hip_bfloat16* __restrict__ y1, const float* __restrict__ adj,
    const __hip_bfloat16* __restrict__ projo, const __hip_bfloat16* __restrict__ mjem_r,
    const float* __restrict__ posw, const float* __restrict__ posb,
    const float* __restrict__ gnfg, const float* __restrict__ gnfb,
    const float* __restrict__ n2g, const float* __restrict__ n2b,
    __hip_bfloat16* __restrict__ resch, __hip_bfloat16* __restrict__ xn2) {
  const int b = blockIdx.x, tid = threadIdx.x;
  __shared__ float xcl[J_][C_];
  __shared__ float adjl[K_ * J_ * J_];
  __shared__ float gstat[16][2];
  __shared__ float lnst[J_][2];
  for (int i = tid; i < K_ * J_ * J_; i += 512) adjl[i] = adj[i];
  if (tid < 32) gstat[tid >> 1][tid & 1] = 0.f;
  __syncthreads();
  const int c = tid;
  float fz[J_];
  if (c < C_) {
    float xnv[J_];
    const __hip_bfloat16* xp = xnT + (size_t)b * J_ * C_ + c;
    #pragma unroll
    for (int j = 0; j < J_; ++j) xnv[j] = b2f(xp[j * C_]);
    float pw[9];
    #pragma unroll
    for (int t = 0; t < 9; ++t) pw[t] = posw[c * 9 + t];
    const float pb = posb[c];
    const __hip_bfloat16* pj = projo + (size_t)b * J_ * C_ + c;
    const __hip_bfloat16* mp = mjem_r + ((size_t)b * C_ + c) * 20;
    #pragma unroll
    for (int j = 0; j < J_; ++j) {
      float pos = pb;
      #pragma unroll
      for (int t = 0; t < 9; ++t) {
        const int jj = j - 4 + t;
        if (jj >= 0 && jj < J_) pos += xnv[jj] * pw[t];
      }
      fz[j] = b2f(pj[j * C_]) + pos + b2f(mp[j]);
    }
    // inline g1 contraction (y1 = cols 1440.. of merged buffer)
    const __hip_bfloat16* yb = y1 + (size_t)b * J_ * NM_ + C3_ + c;
    #pragma unroll
    for (int k = 0; k < K_; ++k) {
      float yv[J_];
      #pragma unroll
      for (int v = 0; v < J_; ++v) yv[v] = b2f(yb[(size_t)v * NM_ + k * C_]);
      #pragma unroll
      for (int j = 0; j < J_; ++j) {
        float acc = 0.f;
        #pragma unroll
        for (int v = 0; v < J_; ++v) acc = fmaf(yv[v], adjl[(k * J_ + v) * J_ + j], acc);
        fz[j] += acc;
      }
    }
    float s = 0.f, sqs = 0.f;
    #pragma unroll
    for (int j = 0; j < J_; ++j) { s += fz[j]; sqs += fz[j] * fz[j]; }
    atomicAdd(&gstat[c / 30][0], s);
    atomicAdd(&gstat[c / 30][1], sqs);
  }
  __syncthreads();
  if (c < C_) {
    const float mu = gstat[c / 30][0] * (1.f / 510.f);
    const float var = gstat[c / 30][1] * (1.f / 510.f) - mu * mu;
    const float rs = rsqrtf(var + EPSF);
    const float sc = gnfg[c], of = gnfb[c];
    const float* xr = x + (size_t)b * J_ * C_ + c;
    __hip_bfloat16* rp = resch + (size_t)b * J_ * C_ + c;
    #pragma unroll
    for (int j = 0; j < J_; ++j) {
      const float xcv = xr[j * C_] + gelu_f((fz[j] - mu) * rs * sc + of);
      xcl[j][c] = xcv;
      rp[j * C_] = f2b(xcv);
    }
  }
  __syncthreads();
  const int wid = tid >> 6, lane = tid & 63;
  for (int j = wid; j < J_; j += 8) {
    float ls = 0.f, lq = 0.f;
    for (int cc = lane; cc < C_; cc += 64) { const float v = xcl[j][cc]; ls += v; lq += v * v; }
    #pragma unroll
    for (int off = 32; off > 0; off >>= 1) { ls += __shfl_xor(ls, off); lq += __shfl_xor(lq, off); }
    if (lane == 0) {
      const float mu = ls * (1.f / C_);
      const float var = lq * (1.f / C_) - mu * mu;
      lnst[j][0] = mu; lnst[j][1] = rsqrtf(var + EPSF);
    }
  }
  __syncthreads();
  if (c < C_) {
    const float sc = n2g[c], of = n2b[c];
    __hip_bfloat16* xp2 = xn2 + (size_t)b * J_ * C_ + c;
    #pragma unroll
    for (int j = 0; j < J_; ++j)
      xp2[j * C_] = f2b((xcl[j][c] - lnst[j][0]) * lnst[j][1] * sc + of);
  }
}

extern "C" void kernel_launch(void* const* d_in, const int* in_sizes, int n_in,
                              void* d_out, int out_size, void* d_ws, size_t ws_size,
                              hipStream_t stream) {
  const float* x      = (const float*)d_in[0];
  const float* adj    = (const float*)d_in[1];
  const float* n1g    = (const float*)d_in[2];
  const float* n1b    = (const float*)d_in[3];
  const float* gcn1_w = (const float*)d_in[4];
  const float* gcn1_b = (const float*)d_in[5];
  const float* dw_w   = (const float*)d_in[6];
  const float* dw_b   = (const float*)d_in[7];
  const float* dwgn_g = (const float*)d_in[8];
  const float* dwgn_b = (const float*)d_in[9];
  const float* m1w1   = (const float*)d_in[10];
  const float* m1b1   = (const float*)d_in[11];
  const float* m1w2   = (const float*)d_in[12];
  const float* m1b2   = (const float*)d_in[13];
  const float* qkv_w  = (const float*)d_in[14];
  const float* qkv_b  = (const float*)d_in[15];
  const float* proj_w = (const float*)d_in[16];
  const float* proj_b = (const float*)d_in[17];
  const float* pos_w  = (const float*)d_in[18];
  const float* pos_b  = (const float*)d_in[19];
  const float* gnf_g  = (const float*)d_in[20];
  const float* gnf_b  = (const float*)d_in[21];
  const float* n2g    = (const float*)d_in[22];
  const float* n2b    = (const float*)d_in[23];
  const float* gcn2_w = (const float*)d_in[24];
  const float* gcn2_b = (const float*)d_in[25];
  const float* m2w1   = (const float*)d_in[26];
  const float* m2b1   = (const float*)d_in[27];
  const float* m2w2   = (const float*)d_in[28];
  const float* m2b2   = (const float*)d_in[29];
  float* out = (float*)d_out;
  char* ws = (char*)d_ws;
  (void)in_sizes; (void)n_in; (void)out_size;

  auto a256 = [](size_t b) { return (b + 255) & ~(size_t)255; };
  const size_t wbytes = 3 * a256((size_t)C3_ * C_ * 2) + a256((size_t)C_ * C_ * 2) +
                        a256((size_t)CH_ * C_ * 2) + a256((size_t)C_ * CH_ * 2);
  int nch = 16;
  for (int cand : {1, 2, 4, 8, 16}) {
    const size_t Bcb = (size_t)(B_ / cand);
    const size_t Mcb = Bcb * J_;
    const size_t fp = wbytes + a256(Mcb * NM_ * 2) + 5 * a256(Mcb * C_ * 2) +
                      a256(Bcb * C_ * 20 * 2) + a256(Bcb * C_ * 32 * 2);
    if (fp <= ws_size) { nch = cand; break; }
  }
  const int Bc = B_ / nch;
  const int Mc = Bc * J_;
  const int nMB = Mc / 128;

  size_t off = 0;
  auto alloc = [&](size_t bytes) { char* p = ws + off; off += a256(bytes); return p; };
  // weight arena: qkv & g1 contiguous (merged GEMM reads 2880 rows starting at w_qkv)
  __hip_bfloat16* w_qkv = (__hip_bfloat16*)alloc((size_t)C3_ * C_ * 2);
  __hip_bfloat16* w_g1  = (__hip_bfloat16*)alloc((size_t)C3_ * C_ * 2);
  __hip_bfloat16* w_g2  = (__hip_bfloat16*)alloc((size_t)C3_ * C_ * 2);
  __hip_bfloat16* w_pr  = (__hip_bfloat16*)alloc((size_t)C_ * C_ * 2);
  __hip_bfloat16* w_21  = (__hip_bfloat16*)alloc((size_t)CH_ * C_ * 2);
  __hip_bfloat16* w_22  = (__hip_bfloat16*)alloc((size_t)C_ * CH_ * 2);
  __hip_bfloat16* BIG   = (__hip_bfloat16*)alloc((size_t)Mc * NM_ * 2);  // merged qkv+y1 -> y2 -> hbuf
  __hip_bfloat16* xnT   = (__hip_bfloat16*)alloc((size_t)Mc * C_ * 2);
  __hip_bfloat16* attno = (__hip_bfloat16*)alloc((size_t)Mc * C_ * 2);   // -> xn2
  __hip_bfloat16* projo = (__hip_bfloat16*)alloc((size_t)Mc * C_ * 2);
  __hip_bfloat16* g2o   = (__hip_bfloat16*)alloc((size_t)Mc * C_ * 2);
  __hip_bfloat16* resch = (__hip_bfloat16*)alloc((size_t)Mc * C_ * 2);
  __hip_bfloat16* mjemr = (__hip_bfloat16*)alloc((size_t)Bc * C_ * 20 * 2);
  __hip_bfloat16* dpr   = (__hip_bfloat16*)alloc((size_t)Bc * C_ * 32 * 2);
  __hip_bfloat16* xn2   = attno;
  __hip_bfloat16* hbuf  = BIG;
  (void)w_g1;

  cvt_all_kernel<<<3150, 256, 0, stream>>>(qkv_w, gcn1_w, gcn2_w, proj_w, m2w1, m2w2, w_qkv);

  for (int ci = 0; ci < nch; ++ci) {
    const float* xc = x + (size_t)ci * Bc * J_ * C_;
    float* outc = out + (size_t)ci * Bc * J_ * C_;
    ln1_kernel<<<(Bc * C_ + 255) / 256, 256, 0, stream>>>(xc, n1g, n1b, xnT, Bc * C_);
    // merged qkv + gcn1 GEMM: N = 2880, bias split at 1440
    gemm_lds<C_, 0><<<dim3(nMB, NM_ / 96), 512, 0, stream>>>(xnT, w_qkv, qkv_b, gcn1_b, C3_,
                                                             BIG, NM_, nullptr, nullptr, nullptr);
    attn_kernel<<<Bc, 512, 0, stream>>>(BIG, attno);
    gemm_lds<C_, 0><<<dim3(nMB, C_ / 96), 512, 0, stream>>>(attno, w_pr, proj_b, proj_b, C_,
                                                            projo, C_, nullptr, nullptr, nullptr);
    dwconv_kernel<<<Bc, 512, 0, stream>>>(xnT, dw_w, dw_b, dwgn_g, dwgn_b, dpr);
    mlp_kernel<<<Bc * 30 / 16, 256, 0, stream>>>(dpr, m1w1, m1b1, m1w2, m1b2, mjemr);
    fuse_kernel<<<Bc, 512, 0, stream>>>(xc, xnT, BIG, adj, projo, mjemr, pos_w, pos_b,
                                        gnf_g, gnf_b, n2g, n2b, resch, xn2);
    // channel stage
    gemm_lds<C_, 0><<<dim3(nMB, C3_ / 96), 512, 0, stream>>>(xn2, w_g2, gcn2_b, gcn2_b, C3_,
                                                             BIG, C3_, nullptr, nullptr, nullptr);
    gcn_contract_kernel<<<Bc, 512, 0, stream>>>(BIG, adj, g2o, C3_, 0);
    gemm_lds<C_, 1><<<dim3(nMB, CH_ / 96), 512, 0, stream>>>(xn2, w_21, m2b1, m2b1, CH_,
                                                             hbuf, CH_, nullptr, nullptr, nullptr);
    gemm_lds<CH_, 2><<<dim3(nMB, C_ / 96), 512, 0, stream>>>(hbuf, w_22, m2b2, m2b2, C_,
                                                             nullptr, C_, resch, g2o, outc);
  }
}

// Round 18
// 761.491 us; speedup vs baseline: 1.2070x; 1.1212x over previous
//
#include <hip/hip_runtime.h>
#include <hip/hip_bf16.h>

#define DI __device__ __forceinline__

typedef __attribute__((ext_vector_type(8))) short bf16x8;
typedef __attribute__((ext_vector_type(4))) float f32x4;

namespace {
constexpr int B_ = 2048, J_ = 17, C_ = 480, K_ = 3, TOK_ = 64, CH_ = 960, H_ = 6, HD_ = 80;
constexpr int C3_ = 3 * C_;            // 1440
constexpr float EPSF = 1e-5f;
}

// branch-free tanh-form GELU
DI float gelu_f(float x) {
  const float kA2 = 2.f * 0.7978845608028654f;
  const float kB2 = 2.f * 0.7978845608028654f * 0.044715f;
  const float z = fmaf(-kB2 * x, x * x, -kA2 * x);
  return x / (1.f + __expf(z));
}
DI float b2f(__hip_bfloat16 v) { return __bfloat162float(v); }
DI __hip_bfloat16 f2b(float v) { return __float2bfloat16(v); }
DI float s2f(short s) { return __uint_as_float(((unsigned)(unsigned short)s) << 16); }
DI unsigned pk2(float a, float b) {
  union { unsigned u; __hip_bfloat16 h[2]; } p;
  p.h[0] = f2b(a); p.h[1] = f2b(b);
  return p.u;
}

DI void gl16(const void* g, void* l) {
  __builtin_amdgcn_global_load_lds(
      (const __attribute__((address_space(1))) unsigned int*)g,
      (__attribute__((address_space(3))) unsigned int*)l, 16, 0, 0);
}

// ---------------- all weights fp32 -> bf16, one kernel (dst arena contiguous) ----------------
__global__ __launch_bounds__(256) void cvt_all_kernel(
    const float* __restrict__ s0, const float* __restrict__ s1,
    const float* __restrict__ s2, const float* __restrict__ s3,
    const float* __restrict__ s4, const float* __restrict__ s5,
    __hip_bfloat16* __restrict__ d) {
  constexpr int SG = C3_ * C_;
  constexpr int O1 = SG, O2 = 2 * SG, O3 = 3 * SG;
  constexpr int O4 = O3 + C_ * C_;
  constexpr int O5 = O4 + CH_ * C_;
  const int i = (blockIdx.x * 256 + threadIdx.x) * 4;
  const float* s; int off;
  if      (i < O1) { s = s0; off = i; }
  else if (i < O2) { s = s1; off = i - O1; }
  else if (i < O3) { s = s2; off = i - O2; }
  else if (i < O4) { s = s3; off = i - O3; }
  else if (i < O5) { s = s4; off = i - O4; }
  else             { s = s5; off = i - O5; }
  const float4 v = *reinterpret_cast<const float4*>(s + off);
  union { ushort4 u; __hip_bfloat16 h[4]; } o;
  o.h[0] = f2b(v.x); o.h[1] = f2b(v.y); o.h[2] = f2b(v.z); o.h[3] = f2b(v.w);
  *reinterpret_cast<ushort4*>(reinterpret_cast<unsigned short*>(d) + i) = o.u;
}

// ---------------- LayerNorm over J ----------------
__global__ __launch_bounds__(256) void ln1_kernel(const float* __restrict__ x,
                                                  const float* __restrict__ g,
                                                  const float* __restrict__ bt,
                                                  __hip_bfloat16* __restrict__ xnT, int nBC) {
  const int t = blockIdx.x * 256 + threadIdx.x;
  if (t >= nBC) return;
  const int b = t / C_, c = t % C_;
  const float* xp = x + (size_t)b * J_ * C_ + c;
  float v[J_];
  float s = 0.f;
  #pragma unroll
  for (int j = 0; j < J_; ++j) { v[j] = xp[j * C_]; s += v[j]; }
  const float mu = s * (1.f / J_);
  float sq = 0.f;
  #pragma unroll
  for (int j = 0; j < J_; ++j) { const float d = v[j] - mu; sq += d * d; }
  const float rs = rsqrtf(sq * (1.f / J_) + EPSF);
  __hip_bfloat16* op = xnT + (size_t)b * J_ * C_ + c;
  #pragma unroll
  for (int j = 0; j < J_; ++j) op[j * C_] = f2b((v[j] - mu) * rs * g[j] + bt[j]);
}

// ---------------- GEMM: BM=128 x BN=160, 8 waves (4m x 2n, 32x80 each), BK=64 ----------------
// LDS 36KB (A 16K + B 20K) -> 4 blocks/CU. 20 MFMA per wave per K-step.
// EPI 0/1: CT-LDS coalesced epilogue in two 64-row passes. EPI 2: f32 acc+bias+r1+r2.
template<int KD, int EPI>
__global__ __launch_bounds__(512) void gemm_lds(const __hip_bfloat16* __restrict__ A,
                                                const __hip_bfloat16* __restrict__ W,
                                                const float* __restrict__ bias,
                                                __hip_bfloat16* __restrict__ Dst, int Ntot,
                                                const __hip_bfloat16* __restrict__ r1,
                                                const __hip_bfloat16* __restrict__ r2,
                                                float* __restrict__ outf) {
  constexpr int NST = (KD + 63) / 64;
  constexpr bool TAIL = (KD % 64) != 0;
  constexpr int ROWB = KD * 2;
  __shared__ __align__(16) char smem[36864];   // A[0,16K) B[16K,36K); epi reuses [0,21504)

  const int m0g = blockIdx.x * 128;
  const int n0g = blockIdx.y * 160;

  const int lane = threadIdx.x & 63;
  const int wid  = threadIdx.x >> 6;
  const int srow = lane >> 3;
  const int scbs = ((lane & 7) * 16) ^ ((srow & 7) << 4);
  auto stage = [&](int t) {
    const int kb = t * 128;
    #pragma unroll
    for (int i = wid; i < 36; i += 8) {   // A chunks 0..15 (128 rows), B chunks 16..35 (160 rows)
      if (i < 16) {
        const int rr = i * 8 + srow;
        gl16((const char*)A + (size_t)(m0g + rr) * ROWB + kb + scbs, smem + i * 1024);
      } else {
        const int rr = (i - 16) * 8 + srow;
        gl16((const char*)W + (size_t)(n0g + rr) * ROWB + kb + scbs, smem + 16384 + (i - 16) * 1024);
      }
    }
  };

  const f32x4 zf = {0.f, 0.f, 0.f, 0.f};
  f32x4 acc[2][5];
  #pragma unroll
  for (int mi = 0; mi < 2; ++mi)
    #pragma unroll
    for (int ni = 0; ni < 5; ++ni) acc[mi][ni] = zf;

  const int rA0 = (wid >> 1) * 32 + (lane & 15);
  const int rB0 = (wid & 1) * 80 + (lane & 15);
  const int swz = (lane & 7) << 4;
  const int kq  = (lane >> 4) * 16;

  for (int t = 0; t < NST; ++t) {
    stage(t);
    __syncthreads();
    const int nks = (TAIL && t == NST - 1) ? 1 : 2;
    for (int ks = 0; ks < nks; ++ks) {
      const int cb = (ks * 64 + kq) ^ swz;
      bf16x8 av[2], bv[5];
      #pragma unroll
      for (int mi = 0; mi < 2; ++mi)
        av[mi] = *reinterpret_cast<const bf16x8*>(smem + (rA0 + mi * 16) * 128 + cb);
      #pragma unroll
      for (int ni = 0; ni < 5; ++ni)
        bv[ni] = *reinterpret_cast<const bf16x8*>(smem + 16384 + (rB0 + ni * 16) * 128 + cb);
      #pragma unroll
      for (int mi = 0; mi < 2; ++mi)
        #pragma unroll
        for (int ni = 0; ni < 5; ++ni)
          acc[mi][ni] = __builtin_amdgcn_mfma_f32_16x16x32_bf16(av[mi], bv[ni], acc[mi][ni], 0, 0, 0);
    }
    __syncthreads();
  }

  // C/D layout: col = lane&15, row = (lane>>4)*4 + reg
  const int lc0 = (wid & 1) * 80 + (lane & 15);
  const int lr0 = (wid >> 1) * 32 + ((lane >> 4) << 2);
  if (EPI == 2) {
    #pragma unroll
    for (int ni = 0; ni < 5; ++ni) {
      const int col = n0g + lc0 + ni * 16;
      const float bvv = bias[col];
      #pragma unroll
      for (int mi = 0; mi < 2; ++mi) {
        #pragma unroll
        for (int r4 = 0; r4 < 4; ++r4) {
          const size_t idx = (size_t)(m0g + lr0 + mi * 16 + r4) * Ntot + col;
          outf[idx] = acc[mi][ni][r4] + bvv + b2f(r1[idx]) + b2f(r2[idx]);
        }
      }
    }
  } else {
    // two 64-row passes through LDS (row stride 336B), then coalesced 320B-row writes
    const int tid = threadIdx.x;
    #pragma unroll
    for (int p = 0; p < 2; ++p) {
      if ((lr0 >> 6) == p) {
        #pragma unroll
        for (int ni = 0; ni < 5; ++ni) {
          const float bvv = bias[n0g + lc0 + ni * 16];
          #pragma unroll
          for (int mi = 0; mi < 2; ++mi) {
            #pragma unroll
            for (int r4 = 0; r4 < 4; ++r4) {
              float v = acc[mi][ni][r4] + bvv;
              if (EPI == 1) v = gelu_f(v);
              ((__hip_bfloat16*)smem)[(lr0 - p * 64 + mi * 16 + r4) * 168 + lc0 + ni * 16] = f2b(v);
            }
          }
        }
      }
      __syncthreads();
      #pragma unroll
      for (int it = 0; it < 3; ++it) {
        const int idx = it * 512 + tid;            // 1280 = 64 rows x 20 slots
        if (idx < 1280) {
          const int row = idx / 20, s = idx - row * 20;
          const uint4 v = *(const uint4*)(smem + row * 336 + s * 16);
          *(uint4*)((char*)Dst + ((size_t)(m0g + p * 64 + row) * Ntot + n0g) * 2 + s * 16) = v;
        }
      }
      __syncthreads();
    }
  }
}

// ---------------- attention: 6 heads x (17x17x80) per b ----------------
__global__ __launch_bounds__(512) void attn_kernel(const __hip_bfloat16* __restrict__ qkv,
                                                   __hip_bfloat16* __restrict__ o) {
  constexpr int SROW = 1448;
  const int b = blockIdx.x, tid = threadIdx.x;
  __shared__ __align__(16) __hip_bfloat16 sqkv[J_ * SROW];
  __shared__ float S[H_][J_][J_];
  {
    const uint4* src = (const uint4*)(qkv + (size_t)b * J_ * C3_);
    uint4* dst = (uint4*)&sqkv[0];
    for (int i = tid; i < 3060; i += 512) {
      const int j = i / 180, u = i - j * 180;
      dst[j * 181 + u] = src[i];
    }
  }
  __syncthreads();
  for (int i = tid; i < H_ * J_ * J_; i += 512) {
    const int h = i / (J_ * J_), r = i % (J_ * J_), qj = r / J_, kj = r % J_;
    const bf16x8* qp = (const bf16x8*)&sqkv[qj * SROW + h * HD_];
    const bf16x8* kp = (const bf16x8*)&sqkv[kj * SROW + C_ + h * HD_];
    float acc = 0.f;
    #pragma unroll
    for (int d8 = 0; d8 < HD_ / 8; ++d8) {
      const bf16x8 qv = qp[d8], kv = kp[d8];
      #pragma unroll
      for (int t = 0; t < 8; ++t) acc += s2f(qv[t]) * s2f(kv[t]);
    }
    S[h][qj][kj] = acc * 0.11180339887498949f;
  }
  __syncthreads();
  if (tid < H_ * J_) {
    const int h = tid / J_, qj = tid % J_;
    float* row = S[h][qj];
    float m = row[0];
    #pragma unroll
    for (int kk = 1; kk < J_; ++kk) m = fmaxf(m, row[kk]);
    float s = 0.f;
    #pragma unroll
    for (int kk = 0; kk < J_; ++kk) { const float e = __expf(row[kk] - m); row[kk] = e; s += e; }
    const float inv = 1.f / s;
    #pragma unroll
    for (int kk = 0; kk < J_; ++kk) row[kk] *= inv;
  }
  __syncthreads();
  __hip_bfloat16* ob = o + (size_t)b * J_ * C_;
  for (int i = tid; i < J_ * C_; i += 512) {
    const int qj = i / C_, c = i % C_;
    const int h = c / HD_;
    const float* srow = S[h][qj];
    float acc = 0.f;
    #pragma unroll
    for (int kk = 0; kk < J_; ++kk) acc += srow[kk] * b2f(sqkv[kk * SROW + 2 * C_ + c]);
    ob[i] = f2b(acc);
  }
}

// ---------------- gcn adjacency contraction ----------------
__global__ __launch_bounds__(512) void gcn_contract_kernel(const __hip_bfloat16* __restrict__ y,
                                                           const float* __restrict__ adj,
                                                           __hip_bfloat16* __restrict__ g) {
  const int b = blockIdx.x, tid = threadIdx.x;
  __shared__ float adjl[K_ * J_ * J_];
  for (int i = tid; i < K_ * J_ * J_; i += 512) adjl[i] = adj[i];
  __syncthreads();
  const int c = tid;
  if (c < C_) {
    float yv[K_][J_];
    const __hip_bfloat16* yb = y + (size_t)b * J_ * C3_ + c;
    #pragma unroll
    for (int k = 0; k < K_; ++k)
      #pragma unroll
      for (int v = 0; v < J_; ++v)
        yv[k][v] = b2f(yb[(size_t)v * C3_ + k * C_]);
    __hip_bfloat16* gp = g + (size_t)b * J_ * C_ + c;
    #pragma unroll
    for (int w = 0; w < J_; ++w) {
      float acc = 0.f;
      #pragma unroll
      for (int k = 0; k < K_; ++k)
        #pragma unroll
        for (int v = 0; v < J_; ++v)
          acc += yv[k][v] * adjl[(k * J_ + v) * J_ + w];
      gp[w * C_] = f2b(acc);
    }
  }
}

// ---------------- dwconv7 + GroupNorm(16) + GELU -> D'[(b*480+c)][32] ----------------
__global__ __launch_bounds__(512) void dwconv_kernel(const __hip_bfloat16* __restrict__ xnT,
    const float* __restrict__ dww, const float* __restrict__ dwb,
    const float* __restrict__ gg, const float* __restrict__ gb,
    __hip_bfloat16* __restrict__ dpr) {
  __shared__ __align__(16) __hip_bfloat16 xl[J_ * C_];
  __shared__ float gstat[16][2];
  const int b = blockIdx.x, tid = threadIdx.x;
  {
    const uint4* src = (const uint4*)(xnT + (size_t)b * J_ * C_);
    uint4* dst = (uint4*)&xl[0];
    for (int i = tid; i < 1020; i += 512) dst[i] = src[i];
  }
  if (tid < 32) gstat[tid >> 1][tid & 1] = 0.f;
  __syncthreads();
  const int c = tid;
  float dv[J_];
  if (c < C_) {
    float xv[J_];
    #pragma unroll
    for (int j = 0; j < J_; ++j) xv[j] = b2f(xl[j * C_ + c]);
    float wv[7];
    #pragma unroll
    for (int t = 0; t < 7; ++t) wv[t] = dww[c * 7 + t];
    const float bias = dwb[c];
    float s = 0.f, sqs = 0.f;
    #pragma unroll
    for (int j = 0; j < J_; ++j) {
      float acc = bias;
      #pragma unroll
      for (int t = 0; t < 7; ++t) {
        const int jj = j - 3 + t;
        if (jj >= 0 && jj < J_) acc = fmaf(xv[jj], wv[t], acc);
      }
      dv[j] = acc; s += acc; sqs += acc * acc;
    }
    atomicAdd(&gstat[c / 30][0], s);
    atomicAdd(&gstat[c / 30][1], sqs);
  }
  __syncthreads();
  if (c < C_) {
    const float mu = gstat[c / 30][0] * (1.f / 510.f);
    const float var = gstat[c / 30][1] * (1.f / 510.f) - mu * mu;
    const float rs = rsqrtf(var + EPSF);
    const float sc = gg[c], of = gb[c];
    #pragma unroll
    for (int j = 0; j < J_; ++j) dv[j] = gelu_f((dv[j] - mu) * rs * sc + of);
    uint4 q0, q1, q2;
    q0.x = pk2(dv[0], dv[1]);   q0.y = pk2(dv[2], dv[3]);
    q0.z = pk2(dv[4], dv[5]);   q0.w = pk2(dv[6], dv[7]);
    q1.x = pk2(dv[8], dv[9]);   q1.y = pk2(dv[10], dv[11]);
    q1.z = pk2(dv[12], dv[13]); q1.w = pk2(dv[14], dv[15]);
    q2.x = pk2(dv[16], 0.f);    q2.y = 0u; q2.z = 0u; q2.w = 0u;
    const uint4 zq = {0u, 0u, 0u, 0u};
    uint4* rp = (uint4*)(dpr + ((size_t)b * C_ + c) * 32);
    rp[0] = q0; rp[1] = q1; rp[2] = q2; rp[3] = zq;
  }
}

// ---------------- token-MLP on MFMA -> mjem_r[(b*480+c)][20] ----------------
__global__ __launch_bounds__(256) void mlp_kernel(const __hip_bfloat16* __restrict__ dpr,
    const float* __restrict__ w1, const float* __restrict__ b1,
    const float* __restrict__ w2, const float* __restrict__ b2,
    __hip_bfloat16* __restrict__ mjem_r) {
  __shared__ __align__(16) char lds[18944];
  constexpr int W1P = 0, W2P = 5120, HS = 9728;
  const int tid = threadIdx.x, lane = tid & 63, wid = tid >> 6;

  {
    __hip_bfloat16* wp = (__hip_bfloat16*)(lds + W1P);
    const int t = tid >> 2, j0 = (tid & 3) * 10;
    #pragma unroll
    for (int e = 0; e < 10; ++e) {
      const int j = j0 + e;
      wp[t * 40 + j] = (j < J_) ? f2b(w1[t * J_ + j]) : f2b(0.f);
    }
  }
  {
    __hip_bfloat16* wp = (__hip_bfloat16*)(lds + W2P);
    const int j = tid >> 3, t0 = (tid & 7) * 9;
    #pragma unroll
    for (int e = 0; e < 9; ++e) {
      const int t = t0 + e;
      wp[j * 72 + t] = (j < J_ && t < TOK_) ? f2b(w2[j * TOK_ + t]) : f2b(0.f);
    }
  }
  __syncthreads();

  const int lr = lane & 15, kc = lane >> 4;
  bf16x8 a1[4];
  #pragma unroll
  for (int mi = 0; mi < 4; ++mi)
    a1[mi] = *(const bf16x8*)(lds + W1P + (lr + mi * 16) * 80 + kc * 16);
  bf16x8 a2[2][2];
  #pragma unroll
  for (int mi = 0; mi < 2; ++mi)
    #pragma unroll
    for (int kk = 0; kk < 2; ++kk)
      a2[mi][kk] = *(const bf16x8*)(lds + W2P + (lr + mi * 16) * 144 + kk * 64 + kc * 16);
  float b1v[4][4];
  #pragma unroll
  for (int mi = 0; mi < 4; ++mi)
    #pragma unroll
    for (int r = 0; r < 4; ++r) b1v[mi][r] = b1[mi * 16 + kc * 4 + r];
  float b2v[4];
  #pragma unroll
  for (int r = 0; r < 4; ++r) b2v[r] = b2[kc * 4 + r];
  const float b2v16 = b2[16];

  char* hs = lds + HS + wid * 2304;
  const f32x4 zf4 = {0.f, 0.f, 0.f, 0.f};
  #pragma unroll
  for (int it = 0; it < 4; ++it) {
    const int gcb = blockIdx.x * 16 + wid * 4 + it;
    const int b = gcb / 30, cbl = gcb - b * 30;
    const size_t row0 = (size_t)b * C_ + cbl * 16;
    const bf16x8 bf = *(const bf16x8*)(dpr + (row0 + lr) * 32 + kc * 8);
    f32x4 acc1[4];
    #pragma unroll
    for (int mi = 0; mi < 4; ++mi)
      acc1[mi] = __builtin_amdgcn_mfma_f32_16x16x32_bf16(a1[mi], bf, zf4, 0, 0, 0);
    #pragma unroll
    for (int mi = 0; mi < 4; ++mi) {
      const float g0 = gelu_f(acc1[mi][0] + b1v[mi][0]);
      const float g1 = gelu_f(acc1[mi][1] + b1v[mi][1]);
      const float g2 = gelu_f(acc1[mi][2] + b1v[mi][2]);
      const float g3 = gelu_f(acc1[mi][3] + b1v[mi][3]);
      unsigned* hp = (unsigned*)(hs + lr * 144 + (mi * 16 + kc * 4) * 2);
      hp[0] = pk2(g0, g1);
      hp[1] = pk2(g2, g3);
    }
    f32x4 acc2[2] = {zf4, zf4};
    #pragma unroll
    for (int kk = 0; kk < 2; ++kk) {
      const bf16x8 hb = *(const bf16x8*)(hs + lr * 144 + kk * 64 + kc * 16);
      #pragma unroll
      for (int mi = 0; mi < 2; ++mi)
        acc2[mi] = __builtin_amdgcn_mfma_f32_16x16x32_bf16(a2[mi][kk], hb, acc2[mi], 0, 0, 0);
    }
    __hip_bfloat16* mp = mjem_r + (row0 + lr) * 20;
    #pragma unroll
    for (int r = 0; r < 4; ++r)
      mp[kc * 4 + r] = f2b(acc2[0][r] + b2v[r]);
    if (kc == 0) mp[16] = f2b(acc2[1][0] + b2v16);
  }
}

// ---------------- fuse: pos-conv + sum + GN + GELU + residual + LN2 ----------------
__global__ __launch_bounds__(512) void fuse_kernel(
    const float* __restrict__ x, const __hip_bfloat16* __restrict__ xnT,
    const __hip_bfloat16* __restrict__ g1o, const __hip_bfloat16* __restrict__ projo,
    const __hip_bfloat16* __restrict__ mjem_r,
    const float* __restrict__ posw, const float* __restrict__ posb,
    const float* __restrict__ gnfg, const float* __restrict__ gnfb,
    const float* __restrict__ n2g, const float* __restrict__ n2b,
    __hip_bfloat16* __restrict__ resch, __hip_bfloat16* __restrict__ xn2) {
  const int b = blockIdx.x, tid = threadIdx.x;
  __shared__ float xcl[J_][C_];
  __shared__ float gstat[16][2];
  __shared__ float lnst[J_][2];
  if (tid < 32) gstat[tid >> 1][tid & 1] = 0.f;
  __syncthreads();
  const int c = tid;
  float fz[J_];
  if (c < C_) {
    float xnv[J_];
    const __hip_bfloat16* xp = xnT + (size_t)b * J_ * C_ + c;
    #pragma unroll
    for (int j = 0; j < J_; ++j) xnv[j] = b2f(xp[j * C_]);
    float pw[9];
    #pragma unroll
    for (int t = 0; t < 9; ++t) pw[t] = posw[c * 9 + t];
    const float pb = posb[c];
    const __hip_bfloat16* pj = projo + (size_t)b * J_ * C_ + c;
    const __hip_bfloat16* mp = mjem_r + ((size_t)b * C_ + c) * 20;
    const __hip_bfloat16* gp = g1o + (size_t)b * J_ * C_ + c;
    float s = 0.f, sqs = 0.f;
    #pragma unroll
    for (int j = 0; j < J_; ++j) {
      float pos = pb;
      #pragma unroll
      for (int t = 0; t < 9; ++t) {
        const int jj = j - 4 + t;
        if (jj >= 0 && jj < J_) pos += xnv[jj] * pw[t];
      }
      const float f = b2f(pj[j * C_]) + pos + b2f(gp[j * C_]) + b2f(mp[j]);
      fz[j] = f; s += f; sqs += f * f;
    }
    atomicAdd(&gstat[c / 30][0], s);
    atomicAdd(&gstat[c / 30][1], sqs);
  }
  __syncthreads();
  if (c < C_) {
    const float mu = gstat[c / 30][0] * (1.f / 510.f);
    const float var = gstat[c / 30][1] * (1.f / 510.f) - mu * mu;
    const float rs = rsqrtf(var + EPSF);
    const float sc = gnfg[c], of = gnfb[c];
    const float* xr = x + (size_t)b * J_ * C_ + c;
    __hip_bfloat16* rp = resch + (size_t)b * J_ * C_ + c;
    #pragma unroll
    for (int j = 0; j < J_; ++j) {
      const float xcv = xr[j * C_] + gelu_f((fz[j] - mu) * rs * sc + of);
      xcl[j][c] = xcv;
      rp[j * C_] = f2b(xcv);
    }
  }
  __syncthreads();
  const int wid = tid >> 6, lane = tid & 63;
  for (int j = wid; j < J_; j += 8) {
    float ls = 0.f, lq = 0.f;
    for (int cc = lane; cc < C_; cc += 64) { const float v = xcl[j][cc]; ls += v; lq += v * v; }
    #pragma unroll
    for (int off = 32; off > 0; off >>= 1) { ls += __shfl_xor(ls, off); lq += __shfl_xor(lq, off); }
    if (lane == 0) {
      const float mu = ls * (1.f / C_);
      const float var = lq * (1.f / C_) - mu * mu;
      lnst[j][0] = mu; lnst[j][1] = rsqrtf(var + EPSF);
    }
  }
  __syncthreads();
  if (c < C_) {
    const float sc = n2g[c], of = n2b[c];
    __hip_bfloat16* xp2 = xn2 + (size_t)b * J_ * C_ + c;
    #pragma unroll
    for (int j = 0; j < J_; ++j)
      xp2[j * C_] = f2b((xcl[j][c] - lnst[j][0]) * lnst[j][1] * sc + of);
  }
}

extern "C" void kernel_launch(void* const* d_in, const int* in_sizes, int n_in,
                              void* d_out, int out_size, void* d_ws, size_t ws_size,
                              hipStream_t stream) {
  const float* x      = (const float*)d_in[0];
  const float* adj    = (const float*)d_in[1];
  const float* n1g    = (const float*)d_in[2];
  const float* n1b    = (const float*)d_in[3];
  const float* gcn1_w = (const float*)d_in[4];
  const float* gcn1_b = (const float*)d_in[5];
  const float* dw_w   = (const float*)d_in[6];
  const float* dw_b   = (const float*)d_in[7];
  const float* dwgn_g = (const float*)d_in[8];
  const float* dwgn_b = (const float*)d_in[9];
  const float* m1w1   = (const float*)d_in[10];
  const float* m1b1   = (const float*)d_in[11];
  const float* m1w2   = (const float*)d_in[12];
  const float* m1b2   = (const float*)d_in[13];
  const float* qkv_w  = (const float*)d_in[14];
  const float* qkv_b  = (const float*)d_in[15];
  const float* proj_w = (const float*)d_in[16];
  const float* proj_b = (const float*)d_in[17];
  const float* pos_w  = (const float*)d_in[18];
  const float* pos_b  = (const float*)d_in[19];
  const float* gnf_g  = (const float*)d_in[20];
  const float* gnf_b  = (const float*)d_in[21];
  const float* n2g    = (const float*)d_in[22];
  const float* n2b    = (const float*)d_in[23];
  const float* gcn2_w = (const float*)d_in[24];
  const float* gcn2_b = (const float*)d_in[25];
  const float* m2w1   = (const float*)d_in[26];
  const float* m2b1   = (const float*)d_in[27];
  const float* m2w2   = (const float*)d_in[28];
  const float* m2b2   = (const float*)d_in[29];
  float* out = (float*)d_out;
  char* ws = (char*)d_ws;
  (void)in_sizes; (void)n_in; (void)out_size;

  auto a256 = [](size_t b) { return (b + 255) & ~(size_t)255; };
  const size_t wbytes = 3 * a256((size_t)C3_ * C_ * 2) + a256((size_t)C_ * C_ * 2) +
                        a256((size_t)CH_ * C_ * 2) + a256((size_t)C_ * CH_ * 2);
  int nch = 16;
  for (int cand : {1, 2, 4, 8, 16}) {
    const size_t Bcb = (size_t)(B_ / cand);
    const size_t Mcb = Bcb * J_;
    const size_t fp = wbytes + a256(Mcb * C3_ * 2) + 5 * a256(Mcb * C_ * 2) +
                      a256(Bcb * C_ * 20 * 2) + a256(Bcb * C_ * 32 * 2);
    if (fp <= ws_size) { nch = cand; break; }
  }
  const int Bc = B_ / nch;
  const int Mc = Bc * J_;
  const int nMB = Mc / 128;

  size_t off = 0;
  auto alloc = [&](size_t bytes) { char* p = ws + off; off += a256(bytes); return p; };
  __hip_bfloat16* w_qkv = (__hip_bfloat16*)alloc((size_t)C3_ * C_ * 2);
  __hip_bfloat16* w_g1  = (__hip_bfloat16*)alloc((size_t)C3_ * C_ * 2);
  __hip_bfloat16* w_g2  = (__hip_bfloat16*)alloc((size_t)C3_ * C_ * 2);
  __hip_bfloat16* w_pr  = (__hip_bfloat16*)alloc((size_t)C_ * C_ * 2);
  __hip_bfloat16* w_21  = (__hip_bfloat16*)alloc((size_t)CH_ * C_ * 2);
  __hip_bfloat16* w_22  = (__hip_bfloat16*)alloc((size_t)C_ * CH_ * 2);
  __hip_bfloat16* BIG   = (__hip_bfloat16*)alloc((size_t)Mc * C3_ * 2);  // qkv -> y1 -> y2 -> hbuf
  __hip_bfloat16* xnT   = (__hip_bfloat16*)alloc((size_t)Mc * C_ * 2);
  __hip_bfloat16* attno = (__hip_bfloat16*)alloc((size_t)Mc * C_ * 2);   // -> xn2
  __hip_bfloat16* projo = (__hip_bfloat16*)alloc((size_t)Mc * C_ * 2);
  __hip_bfloat16* g1o   = (__hip_bfloat16*)alloc((size_t)Mc * C_ * 2);   // -> g2o
  __hip_bfloat16* resch = (__hip_bfloat16*)alloc((size_t)Mc * C_ * 2);
  __hip_bfloat16* mjemr = (__hip_bfloat16*)alloc((size_t)Bc * C_ * 20 * 2);
  __hip_bfloat16* dpr   = (__hip_bfloat16*)alloc((size_t)Bc * C_ * 32 * 2);
  __hip_bfloat16* xn2   = attno;
  __hip_bfloat16* g2o   = g1o;
  __hip_bfloat16* hbuf  = BIG;

  cvt_all_kernel<<<3150, 256, 0, stream>>>(qkv_w, gcn1_w, gcn2_w, proj_w, m2w1, m2w2, w_qkv);

  for (int ci = 0; ci < nch; ++ci) {
    const float* xc = x + (size_t)ci * Bc * J_ * C_;
    float* outc = out + (size_t)ci * Bc * J_ * C_;
    ln1_kernel<<<(Bc * C_ + 255) / 256, 256, 0, stream>>>(xc, n1g, n1b, xnT, Bc * C_);
    gemm_lds<C_, 0><<<dim3(nMB, C3_ / 160), 512, 0, stream>>>(xnT, w_qkv, qkv_b, BIG, C3_, nullptr, nullptr, nullptr);
    attn_kernel<<<Bc, 512, 0, stream>>>(BIG, attno);
    gemm_lds<C_, 0><<<dim3(nMB, C3_ / 160), 512, 0, stream>>>(xnT, w_g1, gcn1_b, BIG, C3_, nullptr, nullptr, nullptr);
    gcn_contract_kernel<<<Bc, 512, 0, stream>>>(BIG, adj, g1o);
    gemm_lds<C_, 0><<<dim3(nMB, C_ / 160), 512, 0, stream>>>(attno, w_pr, proj_b, projo, C_, nullptr, nullptr, nullptr);
    dwconv_kernel<<<Bc, 512, 0, stream>>>(xnT, dw_w, dw_b, dwgn_g, dwgn_b, dpr);
    mlp_kernel<<<Bc * 30 / 16, 256, 0, stream>>>(dpr, m1w1, m1b1, m1w2, m1b2, mjemr);
    fuse_kernel<<<Bc, 512, 0, stream>>>(xc, xnT, g1o, projo, mjemr, pos_w, pos_b,
                                        gnf_g, gnf_b, n2g, n2b, resch, xn2);
    gemm_lds<C_, 0><<<dim3(nMB, C3_ / 160), 512, 0, stream>>>(xn2, w_g2, gcn2_b, BIG, C3_, nullptr, nullptr, nullptr);
    gcn_contract_kernel<<<Bc, 512, 0, stream>>>(BIG, adj, g2o);
    gemm_lds<C_, 1><<<dim3(nMB, CH_ / 160), 512, 0, stream>>>(xn2, w_21, m2b1, hbuf, CH_, nullptr, nullptr, nullptr);
    gemm_lds<CH_, 2><<<dim3(nMB, C_ / 160), 512, 0, stream>>>(hbuf, w_22, m2b2, nullptr, C_, resch, g2o, outc);
  }
}

// Round 19
// 730.428 us; speedup vs baseline: 1.2583x; 1.0425x over previous
//
#include <hip/hip_runtime.h>
#include <hip/hip_bf16.h>

#define DI __device__ __forceinline__

typedef __attribute__((ext_vector_type(8))) short bf16x8;
typedef __attribute__((ext_vector_type(4))) float f32x4;

namespace {
constexpr int B_ = 2048, J_ = 17, C_ = 480, K_ = 3, TOK_ = 64, CH_ = 960, H_ = 6, HD_ = 80;
constexpr int C3_ = 3 * C_;            // 1440
constexpr float EPSF = 1e-5f;
}

// branch-free tanh-form GELU
DI float gelu_f(float x) {
  const float kA2 = 2.f * 0.7978845608028654f;
  const float kB2 = 2.f * 0.7978845608028654f * 0.044715f;
  const float z = fmaf(-kB2 * x, x * x, -kA2 * x);
  return x / (1.f + __expf(z));
}
DI float b2f(__hip_bfloat16 v) { return __bfloat162float(v); }
DI __hip_bfloat16 f2b(float v) { return __float2bfloat16(v); }
DI float s2f(short s) { return __uint_as_float(((unsigned)(unsigned short)s) << 16); }
DI unsigned pk2(float a, float b) {
  union { unsigned u; __hip_bfloat16 h[2]; } p;
  p.h[0] = f2b(a); p.h[1] = f2b(b);
  return p.u;
}

DI void gl16(const void* g, void* l) {
  __builtin_amdgcn_global_load_lds(
      (const __attribute__((address_space(1))) unsigned int*)g,
      (__attribute__((address_space(3))) unsigned int*)l, 16, 0, 0);
}

// ---------------- all weights fp32 -> bf16, one kernel (dst arena contiguous) ----------------
__global__ __launch_bounds__(256) void cvt_all_kernel(
    const float* __restrict__ s0, const float* __restrict__ s1,
    const float* __restrict__ s2, const float* __restrict__ s3,
    const float* __restrict__ s4, const float* __restrict__ s5,
    __hip_bfloat16* __restrict__ d) {
  constexpr int SG = C3_ * C_;
  constexpr int O1 = SG, O2 = 2 * SG, O3 = 3 * SG;
  constexpr int O4 = O3 + C_ * C_;
  constexpr int O5 = O4 + CH_ * C_;
  const int i = (blockIdx.x * 256 + threadIdx.x) * 4;
  const float* s; int off;
  if      (i < O1) { s = s0; off = i; }
  else if (i < O2) { s = s1; off = i - O1; }
  else if (i < O3) { s = s2; off = i - O2; }
  else if (i < O4) { s = s3; off = i - O3; }
  else if (i < O5) { s = s4; off = i - O4; }
  else             { s = s5; off = i - O5; }
  const float4 v = *reinterpret_cast<const float4*>(s + off);
  union { ushort4 u; __hip_bfloat16 h[4]; } o;
  o.h[0] = f2b(v.x); o.h[1] = f2b(v.y); o.h[2] = f2b(v.z); o.h[3] = f2b(v.w);
  *reinterpret_cast<ushort4*>(reinterpret_cast<unsigned short*>(d) + i) = o.u;
}

// ---------------- LayerNorm over J ----------------
__global__ __launch_bounds__(256) void ln1_kernel(const float* __restrict__ x,
                                                  const float* __restrict__ g,
                                                  const float* __restrict__ bt,
                                                  __hip_bfloat16* __restrict__ xnT, int nBC) {
  const int t = blockIdx.x * 256 + threadIdx.x;
  if (t >= nBC) return;
  const int b = t / C_, c = t % C_;
  const float* xp = x + (size_t)b * J_ * C_ + c;
  float v[J_];
  float s = 0.f;
  #pragma unroll
  for (int j = 0; j < J_; ++j) { v[j] = xp[j * C_]; s += v[j]; }
  const float mu = s * (1.f / J_);
  float sq = 0.f;
  #pragma unroll
  for (int j = 0; j < J_; ++j) { const float d = v[j] - mu; sq += d * d; }
  const float rs = rsqrtf(sq * (1.f / J_) + EPSF);
  __hip_bfloat16* op = xnT + (size_t)b * J_ * C_ + c;
  #pragma unroll
  for (int j = 0; j < J_; ++j) op[j * C_] = f2b((v[j] - mu) * rs * g[j] + bt[j]);
}

// ---------------- GEMM: BM=128 x BN=96, 8 waves, BK=64 single-buffer (28 KB LDS) ----------
// EPI 0/1: CT-LDS coalesced epilogue. EPI 2: f32 acc+bias+r1+r2.
template<int KD, int EPI>
__global__ __launch_bounds__(512) void gemm_lds(const __hip_bfloat16* __restrict__ A,
                                                const __hip_bfloat16* __restrict__ W,
                                                const float* __restrict__ bias,
                                                __hip_bfloat16* __restrict__ Dst, int Ntot,
                                                const __hip_bfloat16* __restrict__ r1,
                                                const __hip_bfloat16* __restrict__ r2,
                                                float* __restrict__ outf) {
  constexpr int NST = (KD + 63) / 64;
  constexpr bool TAIL = (KD % 64) != 0;
  constexpr int ROWB = KD * 2;
  __shared__ __align__(16) char smem[28672];   // A[0,16K) B[16K,28K); epi CT 128x208B

  const int m0g = blockIdx.x * 128;
  const int n0g = blockIdx.y * 96;

  const int lane = threadIdx.x & 63;
  const int wid  = threadIdx.x >> 6;
  const int srow = lane >> 3;
  const int scbs = ((lane & 7) * 16) ^ ((srow & 7) << 4);
  auto stage = [&](int t) {
    const int kb = t * 128;
    #pragma unroll
    for (int i = wid; i < 28; i += 8) {
      if (i < 16) {
        const int rr = i * 8 + srow;
        gl16((const char*)A + (size_t)(m0g + rr) * ROWB + kb + scbs, smem + i * 1024);
      } else {
        const int rr = (i - 16) * 8 + srow;
        gl16((const char*)W + (size_t)(n0g + rr) * ROWB + kb + scbs, smem + 16384 + (i - 16) * 1024);
      }
    }
  };

  const f32x4 zf = {0.f, 0.f, 0.f, 0.f};
  f32x4 acc[2][3];
  #pragma unroll
  for (int mi = 0; mi < 2; ++mi)
    #pragma unroll
    for (int ni = 0; ni < 3; ++ni) acc[mi][ni] = zf;

  const int rA0 = (wid >> 1) * 32 + (lane & 15);
  const int rB0 = (wid & 1) * 48 + (lane & 15);
  const int swz = (lane & 7) << 4;
  const int kq  = (lane >> 4) * 16;

  for (int t = 0; t < NST; ++t) {
    stage(t);
    __syncthreads();
    const int nks = (TAIL && t == NST - 1) ? 1 : 2;
    for (int ks = 0; ks < nks; ++ks) {
      const int cb = (ks * 64 + kq) ^ swz;
      bf16x8 av[2], bv[3];
      #pragma unroll
      for (int mi = 0; mi < 2; ++mi)
        av[mi] = *reinterpret_cast<const bf16x8*>(smem + (rA0 + mi * 16) * 128 + cb);
      #pragma unroll
      for (int ni = 0; ni < 3; ++ni)
        bv[ni] = *reinterpret_cast<const bf16x8*>(smem + 16384 + (rB0 + ni * 16) * 128 + cb);
      #pragma unroll
      for (int mi = 0; mi < 2; ++mi)
        #pragma unroll
        for (int ni = 0; ni < 3; ++ni)
          acc[mi][ni] = __builtin_amdgcn_mfma_f32_16x16x32_bf16(av[mi], bv[ni], acc[mi][ni], 0, 0, 0);
    }
    __syncthreads();
  }

  const int lc0 = (wid & 1) * 48 + (lane & 15);
  const int lr0 = (wid >> 1) * 32 + ((lane >> 4) << 2);
  if (EPI == 2) {
    #pragma unroll
    for (int ni = 0; ni < 3; ++ni) {
      const int col = n0g + lc0 + ni * 16;
      const float bvv = bias[col];
      #pragma unroll
      for (int mi = 0; mi < 2; ++mi) {
        #pragma unroll
        for (int r4 = 0; r4 < 4; ++r4) {
          const size_t idx = (size_t)(m0g + lr0 + mi * 16 + r4) * Ntot + col;
          outf[idx] = acc[mi][ni][r4] + bvv + b2f(r1[idx]) + b2f(r2[idx]);
        }
      }
    }
  } else {
    __hip_bfloat16* ct = (__hip_bfloat16*)smem;
    #pragma unroll
    for (int ni = 0; ni < 3; ++ni) {
      const float bvv = bias[n0g + lc0 + ni * 16];
      #pragma unroll
      for (int mi = 0; mi < 2; ++mi) {
        #pragma unroll
        for (int r4 = 0; r4 < 4; ++r4) {
          float v = acc[mi][ni][r4] + bvv;
          if (EPI == 1) v = gelu_f(v);
          ct[(lr0 + mi * 16 + r4) * 104 + lc0 + ni * 16] = f2b(v);
        }
      }
    }
    __syncthreads();
    const int tid = threadIdx.x;
    #pragma unroll
    for (int it = 0; it < 3; ++it) {
      const int idx = it * 512 + tid;              // 1536 = 128 rows x 12 slots
      const int row = idx / 12, s = idx - row * 12;
      const uint4 v = *(const uint4*)(smem + row * 208 + s * 16);
      *(uint4*)((char*)Dst + ((size_t)(m0g + row) * Ntot + n0g) * 2 + s * 16) = v;
    }
  }
}

// ---------------- attention: 6 heads x (17x17x80) per b ----------------
__global__ __launch_bounds__(512) void attn_kernel(const __hip_bfloat16* __restrict__ qkv,
                                                   __hip_bfloat16* __restrict__ o) {
  constexpr int SROW = 1448;
  const int b = blockIdx.x, tid = threadIdx.x;
  __shared__ __align__(16) __hip_bfloat16 sqkv[J_ * SROW];
  __shared__ float S[H_][J_][J_];
  {
    const uint4* src = (const uint4*)(qkv + (size_t)b * J_ * C3_);
    uint4* dst = (uint4*)&sqkv[0];
    for (int i = tid; i < 3060; i += 512) {
      const int j = i / 180, u = i - j * 180;
      dst[j * 181 + u] = src[i];
    }
  }
  __syncthreads();
  for (int i = tid; i < H_ * J_ * J_; i += 512) {
    const int h = i / (J_ * J_), r = i % (J_ * J_), qj = r / J_, kj = r % J_;
    const bf16x8* qp = (const bf16x8*)&sqkv[qj * SROW + h * HD_];
    const bf16x8* kp = (const bf16x8*)&sqkv[kj * SROW + C_ + h * HD_];
    float acc = 0.f;
    #pragma unroll
    for (int d8 = 0; d8 < HD_ / 8; ++d8) {
      const bf16x8 qv = qp[d8], kv = kp[d8];
      #pragma unroll
      for (int t = 0; t < 8; ++t) acc += s2f(qv[t]) * s2f(kv[t]);
    }
    S[h][qj][kj] = acc * 0.11180339887498949f;
  }
  __syncthreads();
  if (tid < H_ * J_) {
    const int h = tid / J_, qj = tid % J_;
    float* row = S[h][qj];
    float m = row[0];
    #pragma unroll
    for (int kk = 1; kk < J_; ++kk) m = fmaxf(m, row[kk]);
    float s = 0.f;
    #pragma unroll
    for (int kk = 0; kk < J_; ++kk) { const float e = __expf(row[kk] - m); row[kk] = e; s += e; }
    const float inv = 1.f / s;
    #pragma unroll
    for (int kk = 0; kk < J_; ++kk) row[kk] *= inv;
  }
  __syncthreads();
  __hip_bfloat16* ob = o + (size_t)b * J_ * C_;
  for (int i = tid; i < J_ * C_; i += 512) {
    const int qj = i / C_, c = i % C_;
    const int h = c / HD_;
    const float* srow = S[h][qj];
    float acc = 0.f;
    #pragma unroll
    for (int kk = 0; kk < J_; ++kk) acc += srow[kk] * b2f(sqkv[kk * SROW + 2 * C_ + c]);
    ob[i] = f2b(acc);
  }
}

// ---------------- gcn adjacency contraction ----------------
__global__ __launch_bounds__(512) void gcn_contract_kernel(const __hip_bfloat16* __restrict__ y,
                                                           const float* __restrict__ adj,
                                                           __hip_bfloat16* __restrict__ g) {
  const int b = blockIdx.x, tid = threadIdx.x;
  __shared__ float adjl[K_ * J_ * J_];
  for (int i = tid; i < K_ * J_ * J_; i += 512) adjl[i] = adj[i];
  __syncthreads();
  const int c = tid;
  if (c < C_) {
    float yv[K_][J_];
    const __hip_bfloat16* yb = y + (size_t)b * J_ * C3_ + c;
    #pragma unroll
    for (int k = 0; k < K_; ++k)
      #pragma unroll
      for (int v = 0; v < J_; ++v)
        yv[k][v] = b2f(yb[(size_t)v * C3_ + k * C_]);
    __hip_bfloat16* gp = g + (size_t)b * J_ * C_ + c;
    #pragma unroll
    for (int w = 0; w < J_; ++w) {
      float acc = 0.f;
      #pragma unroll
      for (int k = 0; k < K_; ++k)
        #pragma unroll
        for (int v = 0; v < J_; ++v)
          acc += yv[k][v] * adjl[(k * J_ + v) * J_ + w];
      gp[w * C_] = f2b(acc);
    }
  }
}

// ---------------- dwconv7 + GroupNorm(16) + GELU -> D'[(b*480+c)][32] ----------------
__global__ __launch_bounds__(512) void dwconv_kernel(const __hip_bfloat16* __restrict__ xnT,
    const float* __restrict__ dww, const float* __restrict__ dwb,
    const float* __restrict__ gg, const float* __restrict__ gb,
    __hip_bfloat16* __restrict__ dpr) {
  __shared__ __align__(16) __hip_bfloat16 xl[J_ * C_];
  __shared__ float gstat[16][2];
  const int b = blockIdx.x, tid = threadIdx.x;
  {
    const uint4* src = (const uint4*)(xnT + (size_t)b * J_ * C_);
    uint4* dst = (uint4*)&xl[0];
    for (int i = tid; i < 1020; i += 512) dst[i] = src[i];
  }
  if (tid < 32) gstat[tid >> 1][tid & 1] = 0.f;
  __syncthreads();
  const int c = tid;
  float dv[J_];
  if (c < C_) {
    float xv[J_];
    #pragma unroll
    for (int j = 0; j < J_; ++j) xv[j] = b2f(xl[j * C_ + c]);
    float wv[7];
    #pragma unroll
    for (int t = 0; t < 7; ++t) wv[t] = dww[c * 7 + t];
    const float bias = dwb[c];
    float s = 0.f, sqs = 0.f;
    #pragma unroll
    for (int j = 0; j < J_; ++j) {
      float acc = bias;
      #pragma unroll
      for (int t = 0; t < 7; ++t) {
        const int jj = j - 3 + t;
        if (jj >= 0 && jj < J_) acc = fmaf(xv[jj], wv[t], acc);
      }
      dv[j] = acc; s += acc; sqs += acc * acc;
    }
    atomicAdd(&gstat[c / 30][0], s);
    atomicAdd(&gstat[c / 30][1], sqs);
  }
  __syncthreads();
  if (c < C_) {
    const float mu = gstat[c / 30][0] * (1.f / 510.f);
    const float var = gstat[c / 30][1] * (1.f / 510.f) - mu * mu;
    const float rs = rsqrtf(var + EPSF);
    const float sc = gg[c], of = gb[c];
    #pragma unroll
    for (int j = 0; j < J_; ++j) dv[j] = gelu_f((dv[j] - mu) * rs * sc + of);
    uint4 q0, q1, q2;
    q0.x = pk2(dv[0], dv[1]);   q0.y = pk2(dv[2], dv[3]);
    q0.z = pk2(dv[4], dv[5]);   q0.w = pk2(dv[6], dv[7]);
    q1.x = pk2(dv[8], dv[9]);   q1.y = pk2(dv[10], dv[11]);
    q1.z = pk2(dv[12], dv[13]); q1.w = pk2(dv[14], dv[15]);
    q2.x = pk2(dv[16], 0.f);    q2.y = 0u; q2.z = 0u; q2.w = 0u;
    const uint4 zq = {0u, 0u, 0u, 0u};
    uint4* rp = (uint4*)(dpr + ((size_t)b * C_ + c) * 32);
    rp[0] = q0; rp[1] = q1; rp[2] = q2; rp[3] = zq;
  }
}

// ---------------- token-MLP on MFMA -> mjem_r[(b*480+c)][20] ----------------
__global__ __launch_bounds__(256) void mlp_kernel(const __hip_bfloat16* __restrict__ dpr,
    const float* __restrict__ w1, const float* __restrict__ b1,
    const float* __restrict__ w2, const float* __restrict__ b2,
    __hip_bfloat16* __restrict__ mjem_r) {
  __shared__ __align__(16) char lds[18944];
  constexpr int W1P = 0, W2P = 5120, HS = 9728;
  const int tid = threadIdx.x, lane = tid & 63, wid = tid >> 6;

  {
    __hip_bfloat16* wp = (__hip_bfloat16*)(lds + W1P);
    const int t = tid >> 2, j0 = (tid & 3) * 10;
    #pragma unroll
    for (int e = 0; e < 10; ++e) {
      const int j = j0 + e;
      wp[t * 40 + j] = (j < J_) ? f2b(w1[t * J_ + j]) : f2b(0.f);
    }
  }
  {
    __hip_bfloat16* wp = (__hip_bfloat16*)(lds + W2P);
    const int j = tid >> 3, t0 = (tid & 7) * 9;
    #pragma unroll
    for (int e = 0; e < 9; ++e) {
      const int t = t0 + e;
      wp[j * 72 + t] = (j < J_ && t < TOK_) ? f2b(w2[j * TOK_ + t]) : f2b(0.f);
    }
  }
  __syncthreads();

  const int lr = lane & 15, kc = lane >> 4;
  bf16x8 a1[4];
  #pragma unroll
  for (int mi = 0; mi < 4; ++mi)
    a1[mi] = *(const bf16x8*)(lds + W1P + (lr + mi * 16) * 80 + kc * 16);
  bf16x8 a2[2][2];
  #pragma unroll
  for (int mi = 0; mi < 2; ++mi)
    #pragma unroll
    for (int kk = 0; kk < 2; ++kk)
      a2[mi][kk] = *(const bf16x8*)(lds + W2P + (lr + mi * 16) * 144 + kk * 64 + kc * 16);
  float b1v[4][4];
  #pragma unroll
  for (int mi = 0; mi < 4; ++mi)
    #pragma unroll
    for (int r = 0; r < 4; ++r) b1v[mi][r] = b1[mi * 16 + kc * 4 + r];
  float b2v[4];
  #pragma unroll
  for (int r = 0; r < 4; ++r) b2v[r] = b2[kc * 4 + r];
  const float b2v16 = b2[16];

  char* hs = lds + HS + wid * 2304;
  const f32x4 zf4 = {0.f, 0.f, 0.f, 0.f};
  #pragma unroll
  for (int it = 0; it < 4; ++it) {
    const int gcb = blockIdx.x * 16 + wid * 4 + it;
    const int b = gcb / 30, cbl = gcb - b * 30;
    const size_t row0 = (size_t)b * C_ + cbl * 16;
    const bf16x8 bf = *(const bf16x8*)(dpr + (row0 + lr) * 32 + kc * 8);
    f32x4 acc1[4];
    #pragma unroll
    for (int mi = 0; mi < 4; ++mi)
      acc1[mi] = __builtin_amdgcn_mfma_f32_16x16x32_bf16(a1[mi], bf, zf4, 0, 0, 0);
    #pragma unroll
    for (int mi = 0; mi < 4; ++mi) {
      const float g0 = gelu_f(acc1[mi][0] + b1v[mi][0]);
      const float g1 = gelu_f(acc1[mi][1] + b1v[mi][1]);
      const float g2 = gelu_f(acc1[mi][2] + b1v[mi][2]);
      const float g3 = gelu_f(acc1[mi][3] + b1v[mi][3]);
      unsigned* hp = (unsigned*)(hs + lr * 144 + (mi * 16 + kc * 4) * 2);
      hp[0] = pk2(g0, g1);
      hp[1] = pk2(g2, g3);
    }
    f32x4 acc2[2] = {zf4, zf4};
    #pragma unroll
    for (int kk = 0; kk < 2; ++kk) {
      const bf16x8 hb = *(const bf16x8*)(hs + lr * 144 + kk * 64 + kc * 16);
      #pragma unroll
      for (int mi = 0; mi < 2; ++mi)
        acc2[mi] = __builtin_amdgcn_mfma_f32_16x16x32_bf16(a2[mi][kk], hb, acc2[mi], 0, 0, 0);
    }
    __hip_bfloat16* mp = mjem_r + (row0 + lr) * 20;
    #pragma unroll
    for (int r = 0; r < 4; ++r)
      mp[kc * 4 + r] = f2b(acc2[0][r] + b2v[r]);
    if (kc == 0) mp[16] = f2b(acc2[1][0] + b2v16);
  }
}

// ---------------- fuse: pos-conv + sum + GN + GELU + residual + LN2 ----------------
__global__ __launch_bounds__(512) void fuse_kernel(
    const float* __restrict__ x, const __hip_bfloat16* __restrict__ xnT,
    const __hip_bfloat16* __restrict__ g1o, const __hip_bfloat16* __restrict__ projo,
    const __hip_bfloat16* __restrict__ mjem_r,
    const float* __restrict__ posw, const float* __restrict__ posb,
    const float* __restrict__ gnfg, const float* __restrict__ gnfb,
    const float* __restrict__ n2g, const float* __restrict__ n2b,
    __hip_bfloat16* __restrict__ resch, __hip_bfloat16* __restrict__ xn2) {
  const int b = blockIdx.x, tid = threadIdx.x;
  __shared__ float xcl[J_][C_];
  __shared__ float gstat[16][2];
  __shared__ float lnst[J_][2];
  if (tid < 32) gstat[tid >> 1][tid & 1] = 0.f;
  __syncthreads();
  const int c = tid;
  float fz[J_];
  if (c < C_) {
    float xnv[J_];
    const __hip_bfloat16* xp = xnT + (size_t)b * J_ * C_ + c;
    #pragma unroll
    for (int j = 0; j < J_; ++j) xnv[j] = b2f(xp[j * C_]);
    float pw[9];
    #pragma unroll
    for (int t = 0; t < 9; ++t) pw[t] = posw[c * 9 + t];
    const float pb = posb[c];
    const __hip_bfloat16* pj = projo + (size_t)b * J_ * C_ + c;
    const __hip_bfloat16* mp = mjem_r + ((size_t)b * C_ + c) * 20;
    const __hip_bfloat16* gp = g1o + (size_t)b * J_ * C_ + c;
    float s = 0.f, sqs = 0.f;
    #pragma unroll
    for (int j = 0; j < J_; ++j) {
      float pos = pb;
      #pragma unroll
      for (int t = 0; t < 9; ++t) {
        const int jj = j - 4 + t;
        if (jj >= 0 && jj < J_) pos += xnv[jj] * pw[t];
      }
      const float f = b2f(pj[j * C_]) + pos + b2f(gp[j * C_]) + b2f(mp[j]);
      fz[j] = f; s += f; sqs += f * f;
    }
    atomicAdd(&gstat[c / 30][0], s);
    atomicAdd(&gstat[c / 30][1], sqs);
  }
  __syncthreads();
  if (c < C_) {
    const float mu = gstat[c / 30][0] * (1.f / 510.f);
    const float var = gstat[c / 30][1] * (1.f / 510.f) - mu * mu;
    const float rs = rsqrtf(var + EPSF);
    const float sc = gnfg[c], of = gnfb[c];
    const float* xr = x + (size_t)b * J_ * C_ + c;
    __hip_bfloat16* rp = resch + (size_t)b * J_ * C_ + c;
    #pragma unroll
    for (int j = 0; j < J_; ++j) {
      const float xcv = xr[j * C_] + gelu_f((fz[j] - mu) * rs * sc + of);
      xcl[j][c] = xcv;
      rp[j * C_] = f2b(xcv);
    }
  }
  __syncthreads();
  const int wid = tid >> 6, lane = tid & 63;
  for (int j = wid; j < J_; j += 8) {
    float ls = 0.f, lq = 0.f;
    for (int cc = lane; cc < C_; cc += 64) { const float v = xcl[j][cc]; ls += v; lq += v * v; }
    #pragma unroll
    for (int off = 32; off > 0; off >>= 1) { ls += __shfl_xor(ls, off); lq += __shfl_xor(lq, off); }
    if (lane == 0) {
      const float mu = ls * (1.f / C_);
      const float var = lq * (1.f / C_) - mu * mu;
      lnst[j][0] = mu; lnst[j][1] = rsqrtf(var + EPSF);
    }
  }
  __syncthreads();
  if (c < C_) {
    const float sc = n2g[c], of = n2b[c];
    __hip_bfloat16* xp2 = xn2 + (size_t)b * J_ * C_ + c;
    #pragma unroll
    for (int j = 0; j < J_; ++j)
      xp2[j * C_] = f2b((xcl[j][c] - lnst[j][0]) * lnst[j][1] * sc + of);
  }
}

extern "C" void kernel_launch(void* const* d_in, const int* in_sizes, int n_in,
                              void* d_out, int out_size, void* d_ws, size_t ws_size,
                              hipStream_t stream) {
  const float* x      = (const float*)d_in[0];
  const float* adj    = (const float*)d_in[1];
  const float* n1g    = (const float*)d_in[2];
  const float* n1b    = (const float*)d_in[3];
  const float* gcn1_w = (const float*)d_in[4];
  const float* gcn1_b = (const float*)d_in[5];
  const float* dw_w   = (const float*)d_in[6];
  const float* dw_b   = (const float*)d_in[7];
  const float* dwgn_g = (const float*)d_in[8];
  const float* dwgn_b = (const float*)d_in[9];
  const float* m1w1   = (const float*)d_in[10];
  const float* m1b1   = (const float*)d_in[11];
  const float* m1w2   = (const float*)d_in[12];
  const float* m1b2   = (const float*)d_in[13];
  const float* qkv_w  = (const float*)d_in[14];
  const float* qkv_b  = (const float*)d_in[15];
  const float* proj_w = (const float*)d_in[16];
  const float* proj_b = (const float*)d_in[17];
  const float* pos_w  = (const float*)d_in[18];
  const float* pos_b  = (const float*)d_in[19];
  const float* gnf_g  = (const float*)d_in[20];
  const float* gnf_b  = (const float*)d_in[21];
  const float* n2g    = (const float*)d_in[22];
  const float* n2b    = (const float*)d_in[23];
  const float* gcn2_w = (const float*)d_in[24];
  const float* gcn2_b = (const float*)d_in[25];
  const float* m2w1   = (const float*)d_in[26];
  const float* m2b1   = (const float*)d_in[27];
  const float* m2w2   = (const float*)d_in[28];
  const float* m2b2   = (const float*)d_in[29];
  float* out = (float*)d_out;
  char* ws = (char*)d_ws;
  (void)in_sizes; (void)n_in; (void)out_size;

  auto a256 = [](size_t b) { return (b + 255) & ~(size_t)255; };
  const size_t wbytes = 3 * a256((size_t)C3_ * C_ * 2) + a256((size_t)C_ * C_ * 2) +
                        a256((size_t)CH_ * C_ * 2) + a256((size_t)C_ * CH_ * 2);
  // tightened footprint: dpr aliases BIG's dead window; buffers = BIG + 5 small + mjemr
  int nch = 16;
  for (int cand : {1, 2, 4, 8, 16}) {
    const size_t Bcb = (size_t)(B_ / cand);
    const size_t Mcb = Bcb * J_;
    const size_t fp = wbytes + a256(Mcb * C3_ * 2) + 5 * a256(Mcb * C_ * 2) +
                      a256(Bcb * C_ * 20 * 2);
    if (fp <= ws_size) { nch = cand; break; }
  }
  const int Bc = B_ / nch;
  const int Mc = Bc * J_;
  const int nMB = Mc / 128;

  size_t off = 0;
  auto alloc = [&](size_t bytes) { char* p = ws + off; off += a256(bytes); return p; };
  __hip_bfloat16* w_qkv = (__hip_bfloat16*)alloc((size_t)C3_ * C_ * 2);
  __hip_bfloat16* w_g1  = (__hip_bfloat16*)alloc((size_t)C3_ * C_ * 2);
  __hip_bfloat16* w_g2  = (__hip_bfloat16*)alloc((size_t)C3_ * C_ * 2);
  __hip_bfloat16* w_pr  = (__hip_bfloat16*)alloc((size_t)C_ * C_ * 2);
  __hip_bfloat16* w_21  = (__hip_bfloat16*)alloc((size_t)CH_ * C_ * 2);
  __hip_bfloat16* w_22  = (__hip_bfloat16*)alloc((size_t)C_ * CH_ * 2);
  __hip_bfloat16* BIG   = (__hip_bfloat16*)alloc((size_t)Mc * C3_ * 2);  // qkv -> y1 -> (dpr) -> y2 -> hbuf
  __hip_bfloat16* xnT   = (__hip_bfloat16*)alloc((size_t)Mc * C_ * 2);
  __hip_bfloat16* attno = (__hip_bfloat16*)alloc((size_t)Mc * C_ * 2);   // -> xn2
  __hip_bfloat16* projo = (__hip_bfloat16*)alloc((size_t)Mc * C_ * 2);
  __hip_bfloat16* g1o   = (__hip_bfloat16*)alloc((size_t)Mc * C_ * 2);   // -> g2o
  __hip_bfloat16* resch = (__hip_bfloat16*)alloc((size_t)Mc * C_ * 2);
  __hip_bfloat16* mjemr = (__hip_bfloat16*)alloc((size_t)Bc * C_ * 20 * 2);
  __hip_bfloat16* xn2   = attno;
  __hip_bfloat16* g2o   = g1o;
  __hip_bfloat16* hbuf  = BIG;
  __hip_bfloat16* dpr   = BIG;   // aliases BIG: live only [dwconv, mlp], inside y1-dead window

  cvt_all_kernel<<<3150, 256, 0, stream>>>(qkv_w, gcn1_w, gcn2_w, proj_w, m2w1, m2w2, w_qkv);

  for (int ci = 0; ci < nch; ++ci) {
    const float* xc = x + (size_t)ci * Bc * J_ * C_;
    float* outc = out + (size_t)ci * Bc * J_ * C_;
    ln1_kernel<<<(Bc * C_ + 255) / 256, 256, 0, stream>>>(xc, n1g, n1b, xnT, Bc * C_);
    gemm_lds<C_, 0><<<dim3(nMB, C3_ / 96), 512, 0, stream>>>(xnT, w_qkv, qkv_b, BIG, C3_, nullptr, nullptr, nullptr);
    attn_kernel<<<Bc, 512, 0, stream>>>(BIG, attno);
    gemm_lds<C_, 0><<<dim3(nMB, C3_ / 96), 512, 0, stream>>>(xnT, w_g1, gcn1_b, BIG, C3_, nullptr, nullptr, nullptr);
    gcn_contract_kernel<<<Bc, 512, 0, stream>>>(BIG, adj, g1o);
    gemm_lds<C_, 0><<<dim3(nMB, C_ / 96), 512, 0, stream>>>(attno, w_pr, proj_b, projo, C_, nullptr, nullptr, nullptr);
    dwconv_kernel<<<Bc, 512, 0, stream>>>(xnT, dw_w, dw_b, dwgn_g, dwgn_b, dpr);
    mlp_kernel<<<Bc * 30 / 16, 256, 0, stream>>>(dpr, m1w1, m1b1, m1w2, m1b2, mjemr);
    fuse_kernel<<<Bc, 512, 0, stream>>>(xc, xnT, g1o, projo, mjemr, pos_w, pos_b,
                                        gnf_g, gnf_b, n2g, n2b, resch, xn2);
    gemm_lds<C_, 0><<<dim3(nMB, C3_ / 96), 512, 0, stream>>>(xn2, w_g2, gcn2_b, BIG, C3_, nullptr, nullptr, nullptr);
    gcn_contract_kernel<<<Bc, 512, 0, stream>>>(BIG, adj, g2o);
    gemm_lds<C_, 1><<<dim3(nMB, CH_ / 96), 512, 0, stream>>>(xn2, w_21, m2b1, hbuf, CH_, nullptr, nullptr, nullptr);
    gemm_lds<CH_, 2><<<dim3(nMB, C_ / 96), 512, 0, stream>>>(hbuf, w_22, m2b2, nullptr, C_, resch, g2o, outc);
  }
}

// Round 20
// 724.518 us; speedup vs baseline: 1.2686x; 1.0082x over previous
//
#include <hip/hip_runtime.h>
#include <hip/hip_bf16.h>

#define DI __device__ __forceinline__

typedef __attribute__((ext_vector_type(8))) short bf16x8;
typedef __attribute__((ext_vector_type(4))) float f32x4;

namespace {
constexpr int B_ = 2048, J_ = 17, C_ = 480, K_ = 3, TOK_ = 64, CH_ = 960, H_ = 6, HD_ = 80;
constexpr int C3_ = 3 * C_;            // 1440
constexpr float EPSF = 1e-5f;
}

// branch-free tanh-form GELU
DI float gelu_f(float x) {
  const float kA2 = 2.f * 0.7978845608028654f;
  const float kB2 = 2.f * 0.7978845608028654f * 0.044715f;
  const float z = fmaf(-kB2 * x, x * x, -kA2 * x);
  return x / (1.f + __expf(z));
}
DI float b2f(__hip_bfloat16 v) { return __bfloat162float(v); }
DI __hip_bfloat16 f2b(float v) { return __float2bfloat16(v); }
DI float s2f(short s) { return __uint_as_float(((unsigned)(unsigned short)s) << 16); }
DI unsigned pk2(float a, float b) {
  union { unsigned u; __hip_bfloat16 h[2]; } p;
  p.h[0] = f2b(a); p.h[1] = f2b(b);
  return p.u;
}

DI void gl16(const void* g, void* l) {
  __builtin_amdgcn_global_load_lds(
      (const __attribute__((address_space(1))) unsigned int*)g,
      (__attribute__((address_space(3))) unsigned int*)l, 16, 0, 0);
}

// ---------------- all weights fp32 -> bf16, one kernel (dst arena contiguous) ----------------
__global__ __launch_bounds__(256) void cvt_all_kernel(
    const float* __restrict__ s0, const float* __restrict__ s1,
    const float* __restrict__ s2, const float* __restrict__ s3,
    const float* __restrict__ s4, const float* __restrict__ s5,
    __hip_bfloat16* __restrict__ d) {
  constexpr int SG = C3_ * C_;
  constexpr int O1 = SG, O2 = 2 * SG, O3 = 3 * SG;
  constexpr int O4 = O3 + C_ * C_;
  constexpr int O5 = O4 + CH_ * C_;
  const int i = (blockIdx.x * 256 + threadIdx.x) * 4;
  const float* s; int off;
  if      (i < O1) { s = s0; off = i; }
  else if (i < O2) { s = s1; off = i - O1; }
  else if (i < O3) { s = s2; off = i - O2; }
  else if (i < O4) { s = s3; off = i - O3; }
  else if (i < O5) { s = s4; off = i - O4; }
  else             { s = s5; off = i - O5; }
  const float4 v = *reinterpret_cast<const float4*>(s + off);
  union { ushort4 u; __hip_bfloat16 h[4]; } o;
  o.h[0] = f2b(v.x); o.h[1] = f2b(v.y); o.h[2] = f2b(v.z); o.h[3] = f2b(v.w);
  *reinterpret_cast<ushort4*>(reinterpret_cast<unsigned short*>(d) + i) = o.u;
}

// ---------------- LayerNorm over J ----------------
__global__ __launch_bounds__(256) void ln1_kernel(const float* __restrict__ x,
                                                  const float* __restrict__ g,
                                                  const float* __restrict__ bt,
                                                  __hip_bfloat16* __restrict__ xnT, int nBC) {
  const int t = blockIdx.x * 256 + threadIdx.x;
  if (t >= nBC) return;
  const int b = t / C_, c = t % C_;
  const float* xp = x + (size_t)b * J_ * C_ + c;
  float v[J_];
  float s = 0.f;
  #pragma unroll
  for (int j = 0; j < J_; ++j) { v[j] = xp[j * C_]; s += v[j]; }
  const float mu = s * (1.f / J_);
  float sq = 0.f;
  #pragma unroll
  for (int j = 0; j < J_; ++j) { const float d = v[j] - mu; sq += d * d; }
  const float rs = rsqrtf(sq * (1.f / J_) + EPSF);
  __hip_bfloat16* op = xnT + (size_t)b * J_ * C_ + c;
  #pragma unroll
  for (int j = 0; j < J_; ++j) op[j * C_] = f2b((v[j] - mu) * rs * g[j] + bt[j]);
}

// ---------------- GEMM: BM=128 x BN=96, 8 waves, BK=64 DOUBLE-buffer (56 KB LDS) ----------
// Prefetch issued BEFORE compute (m97 order): stage(t+1) -> compute(t) -> barrier.
// EPI 0/1: CT-LDS coalesced epilogue (reuses smem). EPI 2: f32 acc+bias+r1+r2.
template<int KD, int EPI>
__global__ __launch_bounds__(512) void gemm_lds(const __hip_bfloat16* __restrict__ A,
                                                const __hip_bfloat16* __restrict__ W,
                                                const float* __restrict__ bias,
                                                __hip_bfloat16* __restrict__ Dst, int Ntot,
                                                const __hip_bfloat16* __restrict__ r1,
                                                const __hip_bfloat16* __restrict__ r2,
                                                float* __restrict__ outf) {
  constexpr int NST = (KD + 63) / 64;
  constexpr bool TAIL = (KD % 64) != 0;
  constexpr int ROWB = KD * 2;
  __shared__ __align__(16) char smem[57344];   // A: 0/16K, B: 32K/44K; epi CT reuses [0,26624)

  const int m0g = blockIdx.x * 128;
  const int n0g = blockIdx.y * 96;

  const int lane = threadIdx.x & 63;
  const int wid  = threadIdx.x >> 6;
  const int srow = lane >> 3;
  const int scbs = ((lane & 7) * 16) ^ ((srow & 7) << 4);
  auto stage = [&](int t, int bi) {
    const int kb = t * 128;
    const int ab = bi * 16384;
    const int bb = 32768 + bi * 12288;
    #pragma unroll
    for (int i = wid; i < 28; i += 8) {
      if (i < 16) {
        const int rr = i * 8 + srow;
        gl16((const char*)A + (size_t)(m0g + rr) * ROWB + kb + scbs, smem + ab + i * 1024);
      } else {
        const int rr = (i - 16) * 8 + srow;
        gl16((const char*)W + (size_t)(n0g + rr) * ROWB + kb + scbs, smem + bb + (i - 16) * 1024);
      }
    }
  };

  const f32x4 zf = {0.f, 0.f, 0.f, 0.f};
  f32x4 acc[2][3];
  #pragma unroll
  for (int mi = 0; mi < 2; ++mi)
    #pragma unroll
    for (int ni = 0; ni < 3; ++ni) acc[mi][ni] = zf;

  const int rA0 = (wid >> 1) * 32 + (lane & 15);
  const int rB0 = (wid & 1) * 48 + (lane & 15);
  const int swz = (lane & 7) << 4;
  const int kq  = (lane >> 4) * 16;

  stage(0, 0);
  __syncthreads();
  int buf = 0;
  for (int t = 0; t < NST; ++t) {
    if (t + 1 < NST) stage(t + 1, buf ^ 1);    // prefetch in flight across compute
    const int abase = buf * 16384;
    const int bbase = 32768 + buf * 12288;
    const int nks = (TAIL && t == NST - 1) ? 1 : 2;
    for (int ks = 0; ks < nks; ++ks) {
      const int cb = (ks * 64 + kq) ^ swz;
      bf16x8 av[2], bv[3];
      #pragma unroll
      for (int mi = 0; mi < 2; ++mi)
        av[mi] = *reinterpret_cast<const bf16x8*>(smem + abase + (rA0 + mi * 16) * 128 + cb);
      #pragma unroll
      for (int ni = 0; ni < 3; ++ni)
        bv[ni] = *reinterpret_cast<const bf16x8*>(smem + bbase + (rB0 + ni * 16) * 128 + cb);
      #pragma unroll
      for (int mi = 0; mi < 2; ++mi)
        #pragma unroll
        for (int ni = 0; ni < 3; ++ni)
          acc[mi][ni] = __builtin_amdgcn_mfma_f32_16x16x32_bf16(av[mi], bv[ni], acc[mi][ni], 0, 0, 0);
    }
    __syncthreads();
    buf ^= 1;
  }

  const int lc0 = (wid & 1) * 48 + (lane & 15);
  const int lr0 = (wid >> 1) * 32 + ((lane >> 4) << 2);
  if (EPI == 2) {
    #pragma unroll
    for (int ni = 0; ni < 3; ++ni) {
      const int col = n0g + lc0 + ni * 16;
      const float bvv = bias[col];
      #pragma unroll
      for (int mi = 0; mi < 2; ++mi) {
        #pragma unroll
        for (int r4 = 0; r4 < 4; ++r4) {
          const size_t idx = (size_t)(m0g + lr0 + mi * 16 + r4) * Ntot + col;
          outf[idx] = acc[mi][ni][r4] + bvv + b2f(r1[idx]) + b2f(r2[idx]);
        }
      }
    }
  } else {
    __hip_bfloat16* ct = (__hip_bfloat16*)smem;
    #pragma unroll
    for (int ni = 0; ni < 3; ++ni) {
      const float bvv = bias[n0g + lc0 + ni * 16];
      #pragma unroll
      for (int mi = 0; mi < 2; ++mi) {
        #pragma unroll
        for (int r4 = 0; r4 < 4; ++r4) {
          float v = acc[mi][ni][r4] + bvv;
          if (EPI == 1) v = gelu_f(v);
          ct[(lr0 + mi * 16 + r4) * 104 + lc0 + ni * 16] = f2b(v);
        }
      }
    }
    __syncthreads();
    const int tid = threadIdx.x;
    #pragma unroll
    for (int it = 0; it < 3; ++it) {
      const int idx = it * 512 + tid;              // 1536 = 128 rows x 12 slots
      const int row = idx / 12, s = idx - row * 12;
      const uint4 v = *(const uint4*)(smem + row * 208 + s * 16);
      *(uint4*)((char*)Dst + ((size_t)(m0g + row) * Ntot + n0g) * 2 + s * 16) = v;
    }
  }
}

// ---------------- attention: 6 heads x (17x17x80) per b ----------------
__global__ __launch_bounds__(512) void attn_kernel(const __hip_bfloat16* __restrict__ qkv,
                                                   __hip_bfloat16* __restrict__ o) {
  constexpr int SROW = 1448;
  const int b = blockIdx.x, tid = threadIdx.x;
  __shared__ __align__(16) __hip_bfloat16 sqkv[J_ * SROW];
  __shared__ float S[H_][J_][J_];
  {
    const uint4* src = (const uint4*)(qkv + (size_t)b * J_ * C3_);
    uint4* dst = (uint4*)&sqkv[0];
    for (int i = tid; i < 3060; i += 512) {
      const int j = i / 180, u = i - j * 180;
      dst[j * 181 + u] = src[i];
    }
  }
  __syncthreads();
  for (int i = tid; i < H_ * J_ * J_; i += 512) {
    const int h = i / (J_ * J_), r = i % (J_ * J_), qj = r / J_, kj = r % J_;
    const bf16x8* qp = (const bf16x8*)&sqkv[qj * SROW + h * HD_];
    const bf16x8* kp = (const bf16x8*)&sqkv[kj * SROW + C_ + h * HD_];
    float acc = 0.f;
    #pragma unroll
    for (int d8 = 0; d8 < HD_ / 8; ++d8) {
      const bf16x8 qv = qp[d8], kv = kp[d8];
      #pragma unroll
      for (int t = 0; t < 8; ++t) acc += s2f(qv[t]) * s2f(kv[t]);
    }
    S[h][qj][kj] = acc * 0.11180339887498949f;
  }
  __syncthreads();
  if (tid < H_ * J_) {
    const int h = tid / J_, qj = tid % J_;
    float* row = S[h][qj];
    float m = row[0];
    #pragma unroll
    for (int kk = 1; kk < J_; ++kk) m = fmaxf(m, row[kk]);
    float s = 0.f;
    #pragma unroll
    for (int kk = 0; kk < J_; ++kk) { const float e = __expf(row[kk] - m); row[kk] = e; s += e; }
    const float inv = 1.f / s;
    #pragma unroll
    for (int kk = 0; kk < J_; ++kk) row[kk] *= inv;
  }
  __syncthreads();
  __hip_bfloat16* ob = o + (size_t)b * J_ * C_;
  for (int i = tid; i < J_ * C_; i += 512) {
    const int qj = i / C_, c = i % C_;
    const int h = c / HD_;
    const float* srow = S[h][qj];
    float acc = 0.f;
    #pragma unroll
    for (int kk = 0; kk < J_; ++kk) acc += srow[kk] * b2f(sqkv[kk * SROW + 2 * C_ + c]);
    ob[i] = f2b(acc);
  }
}

// ---------------- gcn adjacency contraction ----------------
__global__ __launch_bounds__(512) void gcn_contract_kernel(const __hip_bfloat16* __restrict__ y,
                                                           const float* __restrict__ adj,
                                                           __hip_bfloat16* __restrict__ g) {
  const int b = blockIdx.x, tid = threadIdx.x;
  __shared__ float adjl[K_ * J_ * J_];
  for (int i = tid; i < K_ * J_ * J_; i += 512) adjl[i] = adj[i];
  __syncthreads();
  const int c = tid;
  if (c < C_) {
    float yv[K_][J_];
    const __hip_bfloat16* yb = y + (size_t)b * J_ * C3_ + c;
    #pragma unroll
    for (int k = 0; k < K_; ++k)
      #pragma unroll
      for (int v = 0; v < J_; ++v)
        yv[k][v] = b2f(yb[(size_t)v * C3_ + k * C_]);
    __hip_bfloat16* gp = g + (size_t)b * J_ * C_ + c;
    #pragma unroll
    for (int w = 0; w < J_; ++w) {
      float acc = 0.f;
      #pragma unroll
      for (int k = 0; k < K_; ++k)
        #pragma unroll
        for (int v = 0; v < J_; ++v)
          acc += yv[k][v] * adjl[(k * J_ + v) * J_ + w];
      gp[w * C_] = f2b(acc);
    }
  }
}

// ---------------- dwconv7 + GroupNorm(16) + GELU -> D'[(b*480+c)][32] ----------------
__global__ __launch_bounds__(512) void dwconv_kernel(const __hip_bfloat16* __restrict__ xnT,
    const float* __restrict__ dww, const float* __restrict__ dwb,
    const float* __restrict__ gg, const float* __restrict__ gb,
    __hip_bfloat16* __restrict__ dpr) {
  __shared__ __align__(16) __hip_bfloat16 xl[J_ * C_];
  __shared__ float gstat[16][2];
  const int b = blockIdx.x, tid = threadIdx.x;
  {
    const uint4* src = (const uint4*)(xnT + (size_t)b * J_ * C_);
    uint4* dst = (uint4*)&xl[0];
    for (int i = tid; i < 1020; i += 512) dst[i] = src[i];
  }
  if (tid < 32) gstat[tid >> 1][tid & 1] = 0.f;
  __syncthreads();
  const int c = tid;
  float dv[J_];
  if (c < C_) {
    float xv[J_];
    #pragma unroll
    for (int j = 0; j < J_; ++j) xv[j] = b2f(xl[j * C_ + c]);
    float wv[7];
    #pragma unroll
    for (int t = 0; t < 7; ++t) wv[t] = dww[c * 7 + t];
    const float bias = dwb[c];
    float s = 0.f, sqs = 0.f;
    #pragma unroll
    for (int j = 0; j < J_; ++j) {
      float acc = bias;
      #pragma unroll
      for (int t = 0; t < 7; ++t) {
        const int jj = j - 3 + t;
        if (jj >= 0 && jj < J_) acc = fmaf(xv[jj], wv[t], acc);
      }
      dv[j] = acc; s += acc; sqs += acc * acc;
    }
    atomicAdd(&gstat[c / 30][0], s);
    atomicAdd(&gstat[c / 30][1], sqs);
  }
  __syncthreads();
  if (c < C_) {
    const float mu = gstat[c / 30][0] * (1.f / 510.f);
    const float var = gstat[c / 30][1] * (1.f / 510.f) - mu * mu;
    const float rs = rsqrtf(var + EPSF);
    const float sc = gg[c], of = gb[c];
    #pragma unroll
    for (int j = 0; j < J_; ++j) dv[j] = gelu_f((dv[j] - mu) * rs * sc + of);
    uint4 q0, q1, q2;
    q0.x = pk2(dv[0], dv[1]);   q0.y = pk2(dv[2], dv[3]);
    q0.z = pk2(dv[4], dv[5]);   q0.w = pk2(dv[6], dv[7]);
    q1.x = pk2(dv[8], dv[9]);   q1.y = pk2(dv[10], dv[11]);
    q1.z = pk2(dv[12], dv[13]); q1.w = pk2(dv[14], dv[15]);
    q2.x = pk2(dv[16], 0.f);    q2.y = 0u; q2.z = 0u; q2.w = 0u;
    const uint4 zq = {0u, 0u, 0u, 0u};
    uint4* rp = (uint4*)(dpr + ((size_t)b * C_ + c) * 32);
    rp[0] = q0; rp[1] = q1; rp[2] = q2; rp[3] = zq;
  }
}

// ---------------- token-MLP on MFMA -> mjem_r[(b*480+c)][20] ----------------
__global__ __launch_bounds__(256) void mlp_kernel(const __hip_bfloat16* __restrict__ dpr,
    const float* __restrict__ w1, const float* __restrict__ b1,
    const float* __restrict__ w2, const float* __restrict__ b2,
    __hip_bfloat16* __restrict__ mjem_r) {
  __shared__ __align__(16) char lds[18944];
  constexpr int W1P = 0, W2P = 5120, HS = 9728;
  const int tid = threadIdx.x, lane = tid & 63, wid = tid >> 6;

  {
    __hip_bfloat16* wp = (__hip_bfloat16*)(lds + W1P);
    const int t = tid >> 2, j0 = (tid & 3) * 10;
    #pragma unroll
    for (int e = 0; e < 10; ++e) {
      const int j = j0 + e;
      wp[t * 40 + j] = (j < J_) ? f2b(w1[t * J_ + j]) : f2b(0.f);
    }
  }
  {
    __hip_bfloat16* wp = (__hip_bfloat16*)(lds + W2P);
    const int j = tid >> 3, t0 = (tid & 7) * 9;
    #pragma unroll
    for (int e = 0; e < 9; ++e) {
      const int t = t0 + e;
      wp[j * 72 + t] = (j < J_ && t < TOK_) ? f2b(w2[j * TOK_ + t]) : f2b(0.f);
    }
  }
  __syncthreads();

  const int lr = lane & 15, kc = lane >> 4;
  bf16x8 a1[4];
  #pragma unroll
  for (int mi = 0; mi < 4; ++mi)
    a1[mi] = *(const bf16x8*)(lds + W1P + (lr + mi * 16) * 80 + kc * 16);
  bf16x8 a2[2][2];
  #pragma unroll
  for (int mi = 0; mi < 2; ++mi)
    #pragma unroll
    for (int kk = 0; kk < 2; ++kk)
      a2[mi][kk] = *(const bf16x8*)(lds + W2P + (lr + mi * 16) * 144 + kk * 64 + kc * 16);
  float b1v[4][4];
  #pragma unroll
  for (int mi = 0; mi < 4; ++mi)
    #pragma unroll
    for (int r = 0; r < 4; ++r) b1v[mi][r] = b1[mi * 16 + kc * 4 + r];
  float b2v[4];
  #pragma unroll
  for (int r = 0; r < 4; ++r) b2v[r] = b2[kc * 4 + r];
  const float b2v16 = b2[16];

  char* hs = lds + HS + wid * 2304;
  const f32x4 zf4 = {0.f, 0.f, 0.f, 0.f};
  #pragma unroll
  for (int it = 0; it < 4; ++it) {
    const int gcb = blockIdx.x * 16 + wid * 4 + it;
    const int b = gcb / 30, cbl = gcb - b * 30;
    const size_t row0 = (size_t)b * C_ + cbl * 16;
    const bf16x8 bf = *(const bf16x8*)(dpr + (row0 + lr) * 32 + kc * 8);
    f32x4 acc1[4];
    #pragma unroll
    for (int mi = 0; mi < 4; ++mi)
      acc1[mi] = __builtin_amdgcn_mfma_f32_16x16x32_bf16(a1[mi], bf, zf4, 0, 0, 0);
    #pragma unroll
    for (int mi = 0; mi < 4; ++mi) {
      const float g0 = gelu_f(acc1[mi][0] + b1v[mi][0]);
      const float g1 = gelu_f(acc1[mi][1] + b1v[mi][1]);
      const float g2 = gelu_f(acc1[mi][2] + b1v[mi][2]);
      const float g3 = gelu_f(acc1[mi][3] + b1v[mi][3]);
      unsigned* hp = (unsigned*)(hs + lr * 144 + (mi * 16 + kc * 4) * 2);
      hp[0] = pk2(g0, g1);
      hp[1] = pk2(g2, g3);
    }
    f32x4 acc2[2] = {zf4, zf4};
    #pragma unroll
    for (int kk = 0; kk < 2; ++kk) {
      const bf16x8 hb = *(const bf16x8*)(hs + lr * 144 + kk * 64 + kc * 16);
      #pragma unroll
      for (int mi = 0; mi < 2; ++mi)
        acc2[mi] = __builtin_amdgcn_mfma_f32_16x16x32_bf16(a2[mi][kk], hb, acc2[mi], 0, 0, 0);
    }
    __hip_bfloat16* mp = mjem_r + (row0 + lr) * 20;
    #pragma unroll
    for (int r = 0; r < 4; ++r)
      mp[kc * 4 + r] = f2b(acc2[0][r] + b2v[r]);
    if (kc == 0) mp[16] = f2b(acc2[1][0] + b2v16);
  }
}

// ---------------- fuse: pos-conv + sum + GN + GELU + residual + LN2 ----------------
__global__ __launch_bounds__(512) void fuse_kernel(
    const float* __restrict__ x, const __hip_bfloat16* __restrict__ xnT,
    const __hip_bfloat16* __restrict__ g1o, const __hip_bfloat16* __restrict__ projo,
    const __hip_bfloat16* __restrict__ mjem_r,
    const float* __restrict__ posw, const float* __restrict__ posb,
    const float* __restrict__ gnfg, const float* __restrict__ gnfb,
    const float* __restrict__ n2g, const float* __restrict__ n2b,
    __hip_bfloat16* __restrict__ resch, __hip_bfloat16* __restrict__ xn2) {
  const int b = blockIdx.x, tid = threadIdx.x;
  __shared__ float xcl[J_][C_];
  __shared__ float gstat[16][2];
  __shared__ float lnst[J_][2];
  if (tid < 32) gstat[tid >> 1][tid & 1] = 0.f;
  __syncthreads();
  const int c = tid;
  float fz[J_];
  if (c < C_) {
    float xnv[J_];
    const __hip_bfloat16* xp = xnT + (size_t)b * J_ * C_ + c;
    #pragma unroll
    for (int j = 0; j < J_; ++j) xnv[j] = b2f(xp[j * C_]);
    float pw[9];
    #pragma unroll
    for (int t = 0; t < 9; ++t) pw[t] = posw[c * 9 + t];
    const float pb = posb[c];
    const __hip_bfloat16* pj = projo + (size_t)b * J_ * C_ + c;
    const __hip_bfloat16* mp = mjem_r + ((size_t)b * C_ + c) * 20;
    const __hip_bfloat16* gp = g1o + (size_t)b * J_ * C_ + c;
    float s = 0.f, sqs = 0.f;
    #pragma unroll
    for (int j = 0; j < J_; ++j) {
      float pos = pb;
      #pragma unroll
      for (int t = 0; t < 9; ++t) {
        const int jj = j - 4 + t;
        if (jj >= 0 && jj < J_) pos += xnv[jj] * pw[t];
      }
      const float f = b2f(pj[j * C_]) + pos + b2f(gp[j * C_]) + b2f(mp[j]);
      fz[j] = f; s += f; sqs += f * f;
    }
    atomicAdd(&gstat[c / 30][0], s);
    atomicAdd(&gstat[c / 30][1], sqs);
  }
  __syncthreads();
  if (c < C_) {
    const float mu = gstat[c / 30][0] * (1.f / 510.f);
    const float var = gstat[c / 30][1] * (1.f / 510.f) - mu * mu;
    const float rs = rsqrtf(var + EPSF);
    const float sc = gnfg[c], of = gnfb[c];
    const float* xr = x + (size_t)b * J_ * C_ + c;
    __hip_bfloat16* rp = resch + (size_t)b * J_ * C_ + c;
    #pragma unroll
    for (int j = 0; j < J_; ++j) {
      const float xcv = xr[j * C_] + gelu_f((fz[j] - mu) * rs * sc + of);
      xcl[j][c] = xcv;
      rp[j * C_] = f2b(xcv);
    }
  }
  __syncthreads();
  const int wid = tid >> 6, lane = tid & 63;
  for (int j = wid; j < J_; j += 8) {
    float ls = 0.f, lq = 0.f;
    for (int cc = lane; cc < C_; cc += 64) { const float v = xcl[j][cc]; ls += v; lq += v * v; }
    #pragma unroll
    for (int off = 32; off > 0; off >>= 1) { ls += __shfl_xor(ls, off); lq += __shfl_xor(lq, off); }
    if (lane == 0) {
      const float mu = ls * (1.f / C_);
      const float var = lq * (1.f / C_) - mu * mu;
      lnst[j][0] = mu; lnst[j][1] = rsqrtf(var + EPSF);
    }
  }
  __syncthreads();
  if (c < C_) {
    const float sc = n2g[c], of = n2b[c];
    __hip_bfloat16* xp2 = xn2 + (size_t)b * J_ * C_ + c;
    #pragma unroll
    for (int j = 0; j < J_; ++j)
      xp2[j * C_] = f2b((xcl[j][c] - lnst[j][0]) * lnst[j][1] * sc + of);
  }
}

extern "C" void kernel_launch(void* const* d_in, const int* in_sizes, int n_in,
                              void* d_out, int out_size, void* d_ws, size_t ws_size,
                              hipStream_t stream) {
  const float* x      = (const float*)d_in[0];
  const float* adj    = (const float*)d_in[1];
  const float* n1g    = (const float*)d_in[2];
  const float* n1b    = (const float*)d_in[3];
  const float* gcn1_w = (const float*)d_in[4];
  const float* gcn1_b = (const float*)d_in[5];
  const float* dw_w   = (const float*)d_in[6];
  const float* dw_b   = (const float*)d_in[7];
  const float* dwgn_g = (const float*)d_in[8];
  const float* dwgn_b = (const float*)d_in[9];
  const float* m1w1   = (const float*)d_in[10];
  const float* m1b1   = (const float*)d_in[11];
  const float* m1w2   = (const float*)d_in[12];
  const float* m1b2   = (const float*)d_in[13];
  const float* qkv_w  = (const float*)d_in[14];
  const float* qkv_b  = (const float*)d_in[15];
  const float* proj_w = (const float*)d_in[16];
  const float* proj_b = (const float*)d_in[17];
  const float* pos_w  = (const float*)d_in[18];
  const float* pos_b  = (const float*)d_in[19];
  const float* gnf_g  = (const float*)d_in[20];
  const float* gnf_b  = (const float*)d_in[21];
  const float* n2g    = (const float*)d_in[22];
  const float* n2b    = (const float*)d_in[23];
  const float* gcn2_w = (const float*)d_in[24];
  const float* gcn2_b = (const float*)d_in[25];
  const float* m2w1   = (const float*)d_in[26];
  const float* m2b1   = (const float*)d_in[27];
  const float* m2w2   = (const float*)d_in[28];
  const float* m2b2   = (const float*)d_in[29];
  float* out = (float*)d_out;
  char* ws = (char*)d_ws;
  (void)in_sizes; (void)n_in; (void)out_size;

  auto a256 = [](size_t b) { return (b + 255) & ~(size_t)255; };
  const size_t wbytes = 3 * a256((size_t)C3_ * C_ * 2) + a256((size_t)C_ * C_ * 2) +
                        a256((size_t)CH_ * C_ * 2) + a256((size_t)C_ * CH_ * 2);
  int nch = 16;
  for (int cand : {1, 2, 4, 8, 16}) {
    const size_t Bcb = (size_t)(B_ / cand);
    const size_t Mcb = Bcb * J_;
    const size_t fp = wbytes + a256(Mcb * C3_ * 2) + 5 * a256(Mcb * C_ * 2) +
                      a256(Bcb * C_ * 20 * 2);
    if (fp <= ws_size) { nch = cand; break; }
  }
  const int Bc = B_ / nch;
  const int Mc = Bc * J_;
  const int nMB = Mc / 128;

  size_t off = 0;
  auto alloc = [&](size_t bytes) { char* p = ws + off; off += a256(bytes); return p; };
  __hip_bfloat16* w_qkv = (__hip_bfloat16*)alloc((size_t)C3_ * C_ * 2);
  __hip_bfloat16* w_g1  = (__hip_bfloat16*)alloc((size_t)C3_ * C_ * 2);
  __hip_bfloat16* w_g2  = (__hip_bfloat16*)alloc((size_t)C3_ * C_ * 2);
  __hip_bfloat16* w_pr  = (__hip_bfloat16*)alloc((size_t)C_ * C_ * 2);
  __hip_bfloat16* w_21  = (__hip_bfloat16*)alloc((size_t)CH_ * C_ * 2);
  __hip_bfloat16* w_22  = (__hip_bfloat16*)alloc((size_t)C_ * CH_ * 2);
  __hip_bfloat16* BIG   = (__hip_bfloat16*)alloc((size_t)Mc * C3_ * 2);  // qkv -> y1 -> (dpr) -> y2 -> hbuf
  __hip_bfloat16* xnT   = (__hip_bfloat16*)alloc((size_t)Mc * C_ * 2);
  __hip_bfloat16* attno = (__hip_bfloat16*)alloc((size_t)Mc * C_ * 2);   // -> xn2
  __hip_bfloat16* projo = (__hip_bfloat16*)alloc((size_t)Mc * C_ * 2);
  __hip_bfloat16* g1o   = (__hip_bfloat16*)alloc((size_t)Mc * C_ * 2);   // -> g2o
  __hip_bfloat16* resch = (__hip_bfloat16*)alloc((size_t)Mc * C_ * 2);
  __hip_bfloat16* mjemr = (__hip_bfloat16*)alloc((size_t)Bc * C_ * 20 * 2);
  __hip_bfloat16* xn2   = attno;
  __hip_bfloat16* g2o   = g1o;
  __hip_bfloat16* hbuf  = BIG;
  __hip_bfloat16* dpr   = BIG;   // aliases BIG: live only [dwconv, mlp], inside y1-dead window

  cvt_all_kernel<<<3150, 256, 0, stream>>>(qkv_w, gcn1_w, gcn2_w, proj_w, m2w1, m2w2, w_qkv);

  for (int ci = 0; ci < nch; ++ci) {
    const float* xc = x + (size_t)ci * Bc * J_ * C_;
    float* outc = out + (size_t)ci * Bc * J_ * C_;
    ln1_kernel<<<(Bc * C_ + 255) / 256, 256, 0, stream>>>(xc, n1g, n1b, xnT, Bc * C_);
    gemm_lds<C_, 0><<<dim3(nMB, C3_ / 96), 512, 0, stream>>>(xnT, w_qkv, qkv_b, BIG, C3_, nullptr, nullptr, nullptr);
    attn_kernel<<<Bc, 512, 0, stream>>>(BIG, attno);
    gemm_lds<C_, 0><<<dim3(nMB, C3_ / 96), 512, 0, stream>>>(xnT, w_g1, gcn1_b, BIG, C3_, nullptr, nullptr, nullptr);
    gcn_contract_kernel<<<Bc, 512, 0, stream>>>(BIG, adj, g1o);
    gemm_lds<C_, 0><<<dim3(nMB, C_ / 96), 512, 0, stream>>>(attno, w_pr, proj_b, projo, C_, nullptr, nullptr, nullptr);
    dwconv_kernel<<<Bc, 512, 0, stream>>>(xnT, dw_w, dw_b, dwgn_g, dwgn_b, dpr);
    mlp_kernel<<<Bc * 30 / 16, 256, 0, stream>>>(dpr, m1w1, m1b1, m1w2, m1b2, mjemr);
    fuse_kernel<<<Bc, 512, 0, stream>>>(xc, xnT, g1o, projo, mjemr, pos_w, pos_b,
                                        gnf_g, gnf_b, n2g, n2b, resch, xn2);
    gemm_lds<C_, 0><<<dim3(nMB, C3_ / 96), 512, 0, stream>>>(xn2, w_g2, gcn2_b, BIG, C3_, nullptr, nullptr, nullptr);
    gcn_contract_kernel<<<Bc, 512, 0, stream>>>(BIG, adj, g2o);
    gemm_lds<C_, 1><<<dim3(nMB, CH_ / 96), 512, 0, stream>>>(xn2, w_21, m2b1, hbuf, CH_, nullptr, nullptr, nullptr);
    gemm_lds<CH_, 2><<<dim3(nMB, C_ / 96), 512, 0, stream>>>(hbuf, w_22, m2b2, nullptr, C_, resch, g2o, outc);
  }
}